// Round 14
// baseline (1061.739 us; speedup 1.0000x reference)
//
#include <hip/hip_runtime.h>

// Problem dims (fixed by the reference)
#define T_TOK 2048      // B*S tokens
#define H_DIM 2048
#define E_NUM 32
#define I_DIM 1024
#define IS_DIM 2048
#define K_TOT (E_NUM * I_DIM + IS_DIM)   // 34816
#define SLOT_CAP 2048
#define NE_ALL 34        // 32 routed + 2 shared pseudo-experts
#define GU2_TILES 128    // sum ceil(cnt_e/256) <= 96 + 16 shared
#define DN2_TILES 112    // <= 96 + 8 shared (e=32, K=2048)
#define ACT_SLOTS 28672  // sum pad256(cnt_e) (<=24544) + 4096 shared

typedef __bf16 bf16x8 __attribute__((ext_vector_type(8)));
typedef float  f32x4  __attribute__((ext_vector_type(4)));
static_assert(sizeof(bf16x8) == 16, "bf16x8 must be 16B");

// Workspace layout (bytes). Total = 495,273,984 (harness ws >= 579M proven).
// po [ACT_SLOTS][H] bf16 (117.4 MB) ALIASES wgT (134.2 MB, dead after gate_up).
#define OFF_CNT   ((size_t)0)            // cnt[34] int
#define OFF_NTGU  ((size_t)192)
#define OFF_NTDN  ((size_t)196)
#define OFF_BASE  ((size_t)256)          // base[34] int
#define OFF_TGU   ((size_t)512)          // tilesGU[128] uint (step 256)
#define OFF_TDN   ((size_t)1280)         // tilesDN[112] uint (step 256)
#define OFF_PAIRS ((size_t)2048)         // pairs[34][2048] uint
#define OFF_XB    ((size_t)280576)       // xb [T,H] bf16
#define OFF_WGT   ((size_t)8669184)      // wgT [E][I][H] bf16 (po aliases)
#define OFF_PO    OFF_WGT
#define OFF_WUT   ((size_t)142886912)    // wuT [E][I][H] bf16
#define OFF_WSGT  ((size_t)277104640)    // wsgT [IS][H] bf16
#define OFF_WSUT  ((size_t)285493248)    // wsuT [IS][H] bf16
#define OFF_WDT   ((size_t)293881856)    // wdT [H][K_TOT] bf16
#define OFF_ACT   ((size_t)436488192)    // act [28672][1024] bf16 = 58,720,256
#define OFF_TSLOT ((size_t)495208448)    // tslot[T][8] uint = 65,536

__device__ __forceinline__ unsigned short f2bf(float f) {
  unsigned int u = __float_as_uint(f);
  u += 0x7fffu + ((u >> 16) & 1u);   // round-to-nearest-even
  return (unsigned short)(u >> 16);
}

__device__ __forceinline__ void gld16(const void* g, void* l) {
  __builtin_amdgcn_global_load_lds(
      (const __attribute__((address_space(1))) unsigned int*)g,
      (__attribute__((address_space(3))) unsigned int*)l, 16, 0, 0);
}

#define WAITV(N) asm volatile("s_waitcnt vmcnt(" #N ")" ::: "memory")

// ---------------------------------------------------------------------------
// Router: sigmoid(x @ gw^T); top-8; renorm; *2.5 -> pair lists + tslot + xb.
// ---------------------------------------------------------------------------
__global__ __launch_bounds__(256) void router_kernel(
    const float* __restrict__ x, const float* __restrict__ gw,
    int* __restrict__ cnt, unsigned int* __restrict__ pairs,
    unsigned int* __restrict__ tslot, unsigned short* __restrict__ xb)
{
  const int t = blockIdx.x;
  __shared__ float xs[H_DIM];
  __shared__ float sc[E_NUM];
  const float4* xr = (const float4*)(x + (long)t * H_DIM);
  for (int i = threadIdx.x; i < H_DIM / 4; i += 256) ((float4*)xs)[i] = xr[i];
  __syncthreads();
  {
    const int i0 = threadIdx.x * 8;
    ushort4 o1, o2;
    o1.x = f2bf(xs[i0 + 0]); o1.y = f2bf(xs[i0 + 1]);
    o1.z = f2bf(xs[i0 + 2]); o1.w = f2bf(xs[i0 + 3]);
    o2.x = f2bf(xs[i0 + 4]); o2.y = f2bf(xs[i0 + 5]);
    o2.z = f2bf(xs[i0 + 6]); o2.w = f2bf(xs[i0 + 7]);
    *(ushort4*)(xb + (long)t * H_DIM + i0) = o1;
    *(ushort4*)(xb + (long)t * H_DIM + i0 + 4) = o2;
  }
  const int e = threadIdx.x >> 3, p = threadIdx.x & 7;
  const float4* ga = (const float4*)(gw + (long)e * H_DIM);
  const float4* xa = (const float4*)xs;
  float s = 0.f;
  #pragma unroll 4
  for (int i = p * 64; i < p * 64 + 64; ++i) {
    float4 a = ga[i], b = xa[i];
    s += a.x * b.x + a.y * b.y + a.z * b.z + a.w * b.w;
  }
  s += __shfl_down(s, 4, 8);
  s += __shfl_down(s, 2, 8);
  s += __shfl_down(s, 1, 8);
  if (p == 0) sc[e] = 1.f / (1.f + expf(-s));
  __syncthreads();
  if (threadIdx.x == 0) {
    float v[E_NUM];
    #pragma unroll
    for (int i = 0; i < E_NUM; ++i) v[i] = sc[i];
    unsigned mask = 0; float sum = 0.f;
    int sel[8]; float wv[8];
    for (int k = 0; k < 8; ++k) {
      float best = -1.f; int bi = 0;
      for (int i = 0; i < E_NUM; ++i)
        if (!((mask >> i) & 1u) && v[i] > best) { best = v[i]; bi = i; }
      mask |= 1u << bi; sel[k] = bi; wv[k] = best; sum += best;
    }
    const float scale = 2.5f / (sum + 1e-20f);
    for (int k = 0; k < 8; ++k) {
      const int slot = atomicAdd(&cnt[sel[k]], 1);
      if (slot < SLOT_CAP) {
        const unsigned int w16 = (unsigned int)f2bf(wv[k] * scale);
        pairs[sel[k] * SLOT_CAP + slot] = (w16 << 16) | (unsigned int)t;
        tslot[t * 8 + k] = ((unsigned int)sel[k] << 16) | (unsigned int)slot;
      }
    }
  }
}

// ---------------------------------------------------------------------------
// Build 256-step tile lists + pad256 act bases; fill shared pseudo pairs.
// ---------------------------------------------------------------------------
__global__ __launch_bounds__(256) void build_tiles_kernel(
    int* __restrict__ cnt, int* __restrict__ base,
    unsigned int* __restrict__ tgu, int* __restrict__ ntgu,
    unsigned int* __restrict__ tdn, int* __restrict__ ntdn,
    unsigned int* __restrict__ pairs)
{
  const int t = threadIdx.x;
  for (int s = t; s < T_TOK; s += 256) {
    const unsigned int pv = (0x3F80u << 16) | (unsigned int)s;  // w=1.0 bf16
    pairs[32 * SLOT_CAP + s] = pv;
    pairs[33 * SLOT_CAP + s] = pv;
  }
  if (t == 0) {
    cnt[32] = T_TOK; cnt[33] = T_TOK;
    int b = 0, ngu = 0, ndn = 0;
    for (int e = 0; e < NE_ALL; ++e) {
      const int c = (e < 32) ? cnt[e] : T_TOK;
      base[e] = b;
      for (int m0 = 0; m0 < c; m0 += 256) {
        tgu[ngu++] = ((unsigned int)e << 16) | (unsigned int)m0;
        if (e < 33) tdn[ndn++] = ((unsigned int)e << 16) | (unsigned int)m0;
      }
      b += (c + 255) & ~255;
    }
    *ntgu = ngu; *ntdn = ndn;
  }
}

// ---------------------------------------------------------------------------
// Transpose+cvt, 64(c) x 256(r) tiles — at its mixed-stream limit; two
// launches (gate/up weights, down weights).
// ---------------------------------------------------------------------------
struct TDescTable {
  const float* in[6];
  unsigned short* out[6];
  int C[6];
  int ldout[6];
  long in_bs[6];
  long out_bs[6];
  int nbx[6];
  int nbxy[6];
  int start[7];
};

__global__ __launch_bounds__(256) void transpose_fused(TDescTable td)
{
  const int bid = blockIdx.x;
  int i = 0;
  while (i < 5 && bid >= td.start[i + 1]) ++i;
  const int local = bid - td.start[i];
  const int bz = local / td.nbxy[i];
  const int rem = local % td.nbxy[i];
  const int by = rem / td.nbx[i];
  const int bx = rem % td.nbx[i];
  const float* in = td.in[i] + (long)bz * td.in_bs[i];
  unsigned short* out = td.out[i] + (long)bz * td.out_bs[i];
  const int C = td.C[i], ldout = td.ldout[i];

  __shared__ unsigned short tile[64][258];
  const int c0 = bx * 64;
  const int r0 = by * 256;
  const int t = threadIdx.x;
  const int rl0 = t >> 4;
  const int cl0 = (t & 15) * 4;

  float4 v[16];
  #pragma unroll
  for (int p = 0; p < 16; ++p) {
    const int rl = p * 16 + rl0;
    v[p] = *(const float4*)(in + (long)(r0 + rl) * C + c0 + cl0);
  }
  __builtin_amdgcn_sched_barrier(0);
  #pragma unroll
  for (int p = 0; p < 16; ++p) {
    const int rl = p * 16 + rl0;
    tile[cl0 + 0][rl] = f2bf(v[p].x);
    tile[cl0 + 1][rl] = f2bf(v[p].y);
    tile[cl0 + 2][rl] = f2bf(v[p].z);
    tile[cl0 + 3][rl] = f2bf(v[p].w);
  }
  __syncthreads();
  const int cw = t >> 5;
  const int rw = (t & 31) * 8;
  #pragma unroll
  for (int q = 0; q < 8; ++q) {
    const int cl = q * 8 + cw;
    const char* src = (const char*)&tile[cl][rw];
    uint4 o;
    o.x = *(const unsigned int*)(src + 0);
    o.y = *(const unsigned int*)(src + 4);
    o.z = *(const unsigned int*)(src + 8);
    o.w = *(const unsigned int*)(src + 12);
    *(uint4*)(out + (long)(c0 + cl) * ldout + r0 + rw) = o;
  }
}

// ---------------------------------------------------------------------------
// Gate+up GEMM, T3/T4 schedule: 512 thr (8 waves, 4Mx2N), BM=256, BN=64
// (dual B), BK=64, 3-buffer LDS (144KB), counted vmcnt(6) (never 0 mid-loop),
// raw s_barrier, setprio MFMA clusters, XOR-swizzled LDS, gathered A.
// Ledger: tile t's 6 loads issued during t-2; at top(t) outstanding after
// them = t+1's 6 -> WAITV(6) proves t landed; barrier joins all waves;
// buf (t+2)%3's occupant t-1 fully consumed before top barrier of t.
// ---------------------------------------------------------------------------
__global__ __launch_bounds__(512) void gate_up_moe_kernel(
    const unsigned short* __restrict__ xb,
    const unsigned short* __restrict__ bgT,
    const unsigned short* __restrict__ buT,
    const unsigned short* __restrict__ sgT,
    const unsigned short* __restrict__ suT,
    const int* __restrict__ cnt,
    const int* __restrict__ base,
    const unsigned int* __restrict__ pairs,
    const unsigned int* __restrict__ tiles,
    const int* __restrict__ ntp,
    unsigned short* __restrict__ act)
{
  const int ti = blockIdx.y;
  if (ti >= *ntp) return;
  const unsigned int tile = tiles[ti];
  const int e  = (int)(tile >> 16);
  const int m0 = (int)(tile & 0xFFFFu);
  const int cnte = cnt[e];
  const int be = base[e];
  const int n0 = blockIdx.x * 64;
  const long panel = (long)I_DIM * H_DIM;
  const unsigned short* Bg =
      ((e < 32) ? bgT + e * panel : sgT + (e - 32) * panel) + (long)n0 * H_DIM;
  const unsigned short* Bu =
      ((e < 32) ? buT + e * panel : suT + (e - 32) * panel) + (long)n0 * H_DIM;

  __shared__ unsigned short sA[3 * 256 * 64];   // 96KB
  __shared__ unsigned short sBg[3 * 64 * 64];   // 24KB
  __shared__ unsigned short sBu[3 * 64 * 64];   // 24KB

  const int tid = threadIdx.x;
  const int lane = tid & 63;
  const int wid = tid >> 6;            // 0..7
  const int wm = wid >> 1, wn = wid & 1;
  const int l15 = lane & 15;
  const int lk  = (lane >> 4) * 8;
  const int srow = tid >> 3;           // 0..63
  const int scol = (tid & 7) * 8;
  const int scolsw = (((tid & 7) ^ (srow & 7))) * 8;
  const int ksw = (l15 & 7) << 3;

  const unsigned short* asrc[4];
  #pragma unroll
  for (int r = 0; r < 4; ++r) {
    const int slot = m0 + r * 64 + srow;
    const unsigned int pr = (slot < cnte) ? pairs[e * SLOT_CAP + slot] : 0u;
    asrc[r] = xb + (long)(pr & 0xFFFFu) * H_DIM + scolsw;
  }

  const f32x4 fz = {0.f, 0.f, 0.f, 0.f};
  f32x4 accg[4][2], accu[4][2];
  #pragma unroll
  for (int i = 0; i < 4; ++i)
    #pragma unroll
    for (int j = 0; j < 2; ++j) { accg[i][j] = fz; accu[i][j] = fz; }

#define STG_A(buf, k0, r)                                                      \
    gld16(asrc[r] + (k0), sA + (buf) * 16384 + ((r) * 64 + srow) * 64 + scol)
#define STG_BG(buf, k0)                                                        \
    gld16(Bg + (long)srow * H_DIM + (k0) + scolsw,                             \
          sBg + (buf) * 4096 + srow * 64 + scol)
#define STG_BU(buf, k0)                                                        \
    gld16(Bu + (long)srow * H_DIM + (k0) + scolsw,                             \
          sBu + (buf) * 4096 + srow * 64 + scol)

#define CLUSTER_GU(cb, kk) do {                                                \
    const int ko = (kk) * 32 + lk;                                             \
    bf16x8 a[4], g[2], u[2];                                                   \
    _Pragma("unroll")                                                          \
    for (int mi = 0; mi < 4; ++mi)                                             \
      a[mi] = *(const bf16x8*)(sA + (cb) * 16384 +                             \
               (wm * 64 + mi * 16 + l15) * 64 + (ko ^ ksw));                   \
    _Pragma("unroll")                                                          \
    for (int ni = 0; ni < 2; ++ni) {                                           \
      g[ni] = *(const bf16x8*)(sBg + (cb) * 4096 +                             \
               (wn * 32 + ni * 16 + l15) * 64 + (ko ^ ksw));                   \
      u[ni] = *(const bf16x8*)(sBu + (cb) * 4096 +                             \
               (wn * 32 + ni * 16 + l15) * 64 + (ko ^ ksw));                   \
    }                                                                          \
    __builtin_amdgcn_s_setprio(1);                                             \
    _Pragma("unroll")                                                          \
    for (int mi = 0; mi < 4; ++mi)                                             \
      _Pragma("unroll")                                                        \
      for (int ni = 0; ni < 2; ++ni) {                                         \
        accg[mi][ni] = __builtin_amdgcn_mfma_f32_16x16x32_bf16(                \
            a[mi], g[ni], accg[mi][ni], 0, 0, 0);                              \
        accu[mi][ni] = __builtin_amdgcn_mfma_f32_16x16x32_bf16(                \
            a[mi], u[ni], accu[mi][ni], 0, 0, 0);                              \
      }                                                                        \
    __builtin_amdgcn_s_setprio(0);                                             \
  } while (0)

  WAITV(0);                       // drain pairs loads before counting stages
  #pragma unroll
  for (int p = 0; p < 2; ++p) {   // prologue: stage tiles 0,1 (6 loads each)
    const int k0 = p * 64;
    STG_A(p, k0, 0); STG_A(p, k0, 1); STG_BG(p, k0);
    STG_A(p, k0, 2); STG_A(p, k0, 3); STG_BU(p, k0);
  }
  for (int t = 0; t < 32; ++t) {
    const int cb = t % 3;
    const int pb = (t + 2) % 3;
    const int k2 = (t + 2) * 64;
    if (t + 1 < 32) { WAITV(6); } else { WAITV(0); }
    __builtin_amdgcn_s_barrier();
    if (t + 2 < 32) { STG_A(pb, k2, 0); STG_A(pb, k2, 1); STG_BG(pb, k2); }
    CLUSTER_GU(cb, 0);
    __builtin_amdgcn_s_barrier();
    if (t + 2 < 32) { STG_A(pb, k2, 2); STG_A(pb, k2, 3); STG_BU(pb, k2); }
    CLUSTER_GU(cb, 1);
  }
#undef STG_A
#undef STG_BG
#undef STG_BU
#undef CLUSTER_GU

  const int colb = n0 + wn * 32;
  #pragma unroll
  for (int mi = 0; mi < 4; ++mi) {
    #pragma unroll
    for (int r = 0; r < 4; ++r) {
      const int slot = m0 + wm * 64 + mi * 16 + (lane >> 4) * 4 + r;
      if (slot < cnte) {
        const unsigned int pr = pairs[e * SLOT_CAP + slot];
        const float w = __uint_as_float(pr & 0xFFFF0000u);
        #pragma unroll
        for (int ni = 0; ni < 2; ++ni) {
          const float gv = accg[mi][ni][r];
          const float uv = accu[mi][ni][r];
          const float sv = (gv / (1.f + expf(-gv))) * uv * w;
          act[((long)(be + slot)) * I_DIM + colb + ni * 16 + l15] = f2bf(sv);
        }
      }
    }
  }
}

// ---------------------------------------------------------------------------
// Down GEMM, same T3/T4 schedule: 512 thr, BM=256, BN=128, BK=64, 3-buf LDS
// (144KB), vmcnt(6), raw barriers. e=32 runs K=2048 spanning both shared act
// panels. Plain bf16 stores to po (combine kernel sums).
// ---------------------------------------------------------------------------
__global__ __launch_bounds__(512) void down_moe_kernel(
    const unsigned short* __restrict__ act,
    const unsigned short* __restrict__ wdT,
    const int* __restrict__ cnt,
    const int* __restrict__ base,
    const unsigned int* __restrict__ tiles,
    const int* __restrict__ ntp,
    unsigned short* __restrict__ po)
{
  const int ti = blockIdx.y;
  if (ti >= *ntp) return;
  const unsigned int tile = tiles[ti];
  const int e  = (int)(tile >> 16);
  const int m0 = (int)(tile & 0xFFFFu);
  const int cnte = cnt[e];
  const int be = base[e];
  const int n0 = blockIdx.x * 128;
  const unsigned short* A = act + ((long)be + m0) * I_DIM;
  const unsigned short* B = wdT + (long)n0 * K_TOT + (long)e * I_DIM;
  const int nk = (e == 32) ? 32 : 16;

  __shared__ unsigned short sA[3 * 256 * 64];   // 96KB
  __shared__ unsigned short sB[3 * 128 * 64];   // 48KB

  const int tid = threadIdx.x;
  const int lane = tid & 63;
  const int wid = tid >> 6;
  const int wm = wid >> 1, wn = wid & 1;
  const int l15 = lane & 15;
  const int lk  = (lane >> 4) * 8;
  const int srow = tid >> 3;           // 0..63
  const int scol = (tid & 7) * 8;
  const int scolsw = (((tid & 7) ^ (srow & 7))) * 8;
  const int ksw = (l15 & 7) << 3;

  const f32x4 fz = {0.f, 0.f, 0.f, 0.f};
  f32x4 acc[4][4];
  #pragma unroll
  for (int i = 0; i < 4; ++i)
    #pragma unroll
    for (int j = 0; j < 4; ++j) acc[i][j] = fz;

#define KOFF(k0) ((long)((k0) & 1023) + (long)((k0) >> 10) * (2048L * 1024L))
#define STG_A(buf, k0, r)                                                      \
    gld16(A + (long)((r) * 64 + srow) * I_DIM + KOFF(k0) + scolsw,             \
          sA + (buf) * 16384 + ((r) * 64 + srow) * 64 + scol)
#define STG_B(buf, k0, r)                                                      \
    gld16(B + (long)((r) * 64 + srow) * K_TOT + (k0) + scolsw,                 \
          sB + (buf) * 8192 + ((r) * 64 + srow) * 64 + scol)

#define CLUSTER_DN(cb, kk) do {                                                \
    const int ko = (kk) * 32 + lk;                                             \
    bf16x8 a[4], b[4];                                                         \
    _Pragma("unroll")                                                          \
    for (int mi = 0; mi < 4; ++mi)                                             \
      a[mi] = *(const bf16x8*)(sA + (cb) * 16384 +                             \
               (wm * 64 + mi * 16 + l15) * 64 + (ko ^ ksw));                   \
    _Pragma("unroll")                                                          \
    for (int ni = 0; ni < 4; ++ni)                                             \
      b[ni] = *(const bf16x8*)(sB + (cb) * 8192 +                              \
               (wn * 64 + ni * 16 + l15) * 64 + (ko ^ ksw));                   \
    __builtin_amdgcn_s_setprio(1);                                             \
    _Pragma("unroll")                                                          \
    for (int mi = 0; mi < 4; ++mi)                                             \
      _Pragma("unroll")                                                        \
      for (int ni = 0; ni < 4; ++ni)                                           \
        acc[mi][ni] = __builtin_amdgcn_mfma_f32_16x16x32_bf16(                 \
            a[mi], b[ni], acc[mi][ni], 0, 0, 0);                               \
    __builtin_amdgcn_s_setprio(0);                                             \
  } while (0)

  WAITV(0);
  #pragma unroll
  for (int p = 0; p < 2; ++p) {
    const int k0 = p * 64;
    STG_A(p, k0, 0); STG_A(p, k0, 1); STG_B(p, k0, 0);
    STG_A(p, k0, 2); STG_A(p, k0, 3); STG_B(p, k0, 1);
  }
  for (int t = 0; t < nk; ++t) {
    const int cb = t % 3;
    const int pb = (t + 2) % 3;
    const int k2 = (t + 2) * 64;
    if (t + 1 < nk) { WAITV(6); } else { WAITV(0); }
    __builtin_amdgcn_s_barrier();
    if (t + 2 < nk) { STG_A(pb, k2, 0); STG_A(pb, k2, 1); STG_B(pb, k2, 0); }
    CLUSTER_DN(cb, 0);
    __builtin_amdgcn_s_barrier();
    if (t + 2 < nk) { STG_A(pb, k2, 2); STG_A(pb, k2, 3); STG_B(pb, k2, 1); }
    CLUSTER_DN(cb, 1);
  }
#undef KOFF
#undef STG_A
#undef STG_B
#undef CLUSTER_DN

  #pragma unroll
  for (int mi = 0; mi < 4; ++mi) {
    #pragma unroll
    for (int r = 0; r < 4; ++r) {
      const int slot = m0 + wm * 64 + mi * 16 + (lane >> 4) * 4 + r;
      if (slot < cnte) {
        unsigned short* pr = po + (long)(be + slot) * H_DIM + n0 + wn * 64;
        #pragma unroll
        for (int ni = 0; ni < 4; ++ni)
          pr[ni * 16 + l15] = f2bf(acc[mi][ni][r]);
      }
    }
  }
}

// ---------------------------------------------------------------------------
// Combine: out[t][h] = sum of token's 8 routed partial rows + shared row.
// ---------------------------------------------------------------------------
__global__ __launch_bounds__(256) void combine_kernel(
    const unsigned short* __restrict__ po,
    const int* __restrict__ base,
    const unsigned int* __restrict__ tslot,
    float* __restrict__ out)
{
  const int t = blockIdx.x;
  __shared__ int rows[9];
  if (threadIdx.x < 8) {
    const unsigned int pr = tslot[t * 8 + threadIdx.x];
    rows[threadIdx.x] = base[pr >> 16] + (int)(pr & 0xFFFFu);
  }
  if (threadIdx.x == 8) rows[8] = base[32] + t;
  __syncthreads();
  const int col = threadIdx.x * 8;
  float s[8];
  #pragma unroll
  for (int j = 0; j < 8; ++j) s[j] = 0.f;
  #pragma unroll
  for (int k = 0; k < 9; ++k) {
    const ushort4* p = (const ushort4*)(po + (long)rows[k] * H_DIM + col);
    const ushort4 v0 = p[0], v1 = p[1];
    s[0] += __uint_as_float((unsigned int)v0.x << 16);
    s[1] += __uint_as_float((unsigned int)v0.y << 16);
    s[2] += __uint_as_float((unsigned int)v0.z << 16);
    s[3] += __uint_as_float((unsigned int)v0.w << 16);
    s[4] += __uint_as_float((unsigned int)v1.x << 16);
    s[5] += __uint_as_float((unsigned int)v1.y << 16);
    s[6] += __uint_as_float((unsigned int)v1.z << 16);
    s[7] += __uint_as_float((unsigned int)v1.w << 16);
  }
  float4 o0 = {s[0], s[1], s[2], s[3]};
  float4 o1 = {s[4], s[5], s[6], s[7]};
  *(float4*)(out + (long)t * H_DIM + col) = o0;
  *(float4*)(out + (long)t * H_DIM + col + 4) = o1;
}

// ---------------------------------------------------------------------------
extern "C" void kernel_launch(void* const* d_in, const int* in_sizes, int n_in,
                              void* d_out, int out_size, void* d_ws, size_t ws_size,
                              hipStream_t stream) {
  (void)in_sizes; (void)n_in; (void)out_size; (void)ws_size;
  const float* x   = (const float*)d_in[0];
  const float* gw  = (const float*)d_in[1];
  const float* wg  = (const float*)d_in[2];
  const float* wu  = (const float*)d_in[3];
  const float* wd  = (const float*)d_in[4];
  const float* wsg = (const float*)d_in[5];
  const float* wsu = (const float*)d_in[6];
  const float* wsd = (const float*)d_in[7];
  float* out = (float*)d_out;
  char* ws = (char*)d_ws;

  int*            cnt   = (int*)(ws + OFF_CNT);
  int*            ntgu  = (int*)(ws + OFF_NTGU);
  int*            ntdn  = (int*)(ws + OFF_NTDN);
  int*            basep = (int*)(ws + OFF_BASE);
  unsigned int*   tgu   = (unsigned int*)(ws + OFF_TGU);
  unsigned int*   tdn   = (unsigned int*)(ws + OFF_TDN);
  unsigned int*   pairs = (unsigned int*)(ws + OFF_PAIRS);
  unsigned int*   tslot = (unsigned int*)(ws + OFF_TSLOT);
  unsigned short* xb    = (unsigned short*)(ws + OFF_XB);
  unsigned short* wgT   = (unsigned short*)(ws + OFF_WGT);
  unsigned short* wuT   = (unsigned short*)(ws + OFF_WUT);
  unsigned short* wsgT  = (unsigned short*)(ws + OFF_WSGT);
  unsigned short* wsuT  = (unsigned short*)(ws + OFF_WSUT);
  unsigned short* wdT   = (unsigned short*)(ws + OFF_WDT);
  unsigned short* actb  = (unsigned short*)(ws + OFF_ACT);
  unsigned short* pob   = (unsigned short*)(ws + OFF_PO);   // aliases wgT

  hipMemsetAsync(ws + OFF_CNT, 0, 256, stream);

  router_kernel<<<T_TOK, 256, 0, stream>>>(x, gw, cnt, pairs, tslot, xb);
  build_tiles_kernel<<<1, 256, 0, stream>>>(cnt, basep, tgu, ntgu, tdn, ntdn,
                                            pairs);

  // transpose A: gate/up weights
  TDescTable ta;
  ta.in[0] = wg;  ta.out[0] = wgT;  ta.C[0] = I_DIM;  ta.ldout[0] = H_DIM;
  ta.in_bs[0] = (long)H_DIM * I_DIM; ta.out_bs[0] = (long)I_DIM * H_DIM;
  ta.nbx[0] = I_DIM / 64; ta.nbxy[0] = (I_DIM / 64) * (H_DIM / 256);
  ta.in[1] = wu;  ta.out[1] = wuT;  ta.C[1] = I_DIM;  ta.ldout[1] = H_DIM;
  ta.in_bs[1] = (long)H_DIM * I_DIM; ta.out_bs[1] = (long)I_DIM * H_DIM;
  ta.nbx[1] = I_DIM / 64; ta.nbxy[1] = (I_DIM / 64) * (H_DIM / 256);
  ta.in[2] = wsg; ta.out[2] = wsgT; ta.C[2] = IS_DIM; ta.ldout[2] = H_DIM;
  ta.in_bs[2] = 0; ta.out_bs[2] = 0;
  ta.nbx[2] = IS_DIM / 64; ta.nbxy[2] = (IS_DIM / 64) * (H_DIM / 256);
  ta.in[3] = wsu; ta.out[3] = wsuT; ta.C[3] = IS_DIM; ta.ldout[3] = H_DIM;
  ta.in_bs[3] = 0; ta.out_bs[3] = 0;
  ta.nbx[3] = IS_DIM / 64; ta.nbxy[3] = (IS_DIM / 64) * (H_DIM / 256);
  for (int i = 4; i < 6; ++i) {
    ta.in[i] = ta.in[3]; ta.out[i] = ta.out[3]; ta.C[i] = ta.C[3];
    ta.ldout[i] = ta.ldout[3]; ta.in_bs[i] = 0; ta.out_bs[i] = 0;
    ta.nbx[i] = 1; ta.nbxy[i] = 1;
  }
  ta.start[0] = 0;
  ta.start[1] = ta.start[0] + ta.nbxy[0] * E_NUM;
  ta.start[2] = ta.start[1] + ta.nbxy[1] * E_NUM;
  ta.start[3] = ta.start[2] + ta.nbxy[2];
  ta.start[4] = ta.start[3] + ta.nbxy[3];
  ta.start[5] = ta.start[4];
  ta.start[6] = ta.start[4];
  transpose_fused<<<ta.start[4], 256, 0, stream>>>(ta);

  // gate+up (routed + shared pseudo-experts) -> compact act
  gate_up_moe_kernel<<<dim3(16, GU2_TILES), 512, 0, stream>>>(
      xb, wgT, wuT, wsgT, wsuT, cnt, basep, pairs, tgu, ntgu, actb);

  // transpose B: down weights (wgT dead now; po aliases it)
  TDescTable tb;
  tb.in[0] = wd;  tb.out[0] = wdT;  tb.C[0] = H_DIM;  tb.ldout[0] = K_TOT;
  tb.in_bs[0] = (long)I_DIM * H_DIM; tb.out_bs[0] = (long)I_DIM;
  tb.nbx[0] = H_DIM / 64; tb.nbxy[0] = (H_DIM / 64) * (I_DIM / 256);
  tb.in[1] = wsd; tb.out[1] = wdT + E_NUM * I_DIM; tb.C[1] = H_DIM;
  tb.ldout[1] = K_TOT; tb.in_bs[1] = 0; tb.out_bs[1] = 0;
  tb.nbx[1] = H_DIM / 64; tb.nbxy[1] = (H_DIM / 64) * (IS_DIM / 256);
  for (int i = 2; i < 6; ++i) {
    tb.in[i] = tb.in[1]; tb.out[i] = tb.out[1]; tb.C[i] = tb.C[1];
    tb.ldout[i] = tb.ldout[1]; tb.in_bs[i] = 0; tb.out_bs[i] = 0;
    tb.nbx[i] = 1; tb.nbxy[i] = 1;
  }
  tb.start[0] = 0;
  tb.start[1] = tb.start[0] + tb.nbxy[0] * E_NUM;
  tb.start[2] = tb.start[1] + tb.nbxy[1];
  tb.start[3] = tb.start[2];
  tb.start[4] = tb.start[2];
  tb.start[5] = tb.start[2];
  tb.start[6] = tb.start[2];
  transpose_fused<<<tb.start[2], 256, 0, stream>>>(tb);

  // down (routed K=1024, shared K=2048) -> plain-store partials
  down_moe_kernel<<<dim3(16, DN2_TILES), 512, 0, stream>>>(
      actb, wdT, cnt, basep, tdn, ntdn, pob);

  // gather-combine: 9 partial rows per token -> out
  combine_kernel<<<T_TOK, 256, 0, stream>>>(pob, basep, tslot, out);
}

// Round 15
// 867.579 us; speedup vs baseline: 1.2238x; 1.2238x over previous
//
#include <hip/hip_runtime.h>

// Problem dims (fixed by the reference)
#define T_TOK 2048      // B*S tokens
#define H_DIM 2048
#define E_NUM 32
#define I_DIM 1024
#define IS_DIM 2048
#define K_TOT (E_NUM * I_DIM + IS_DIM)   // 34816
#define SLOT_CAP 2048
#define NE_ALL 34        // 32 routed + 2 shared pseudo-experts
#define GU_TILES 192     // <=160 routed + 32 shared (step 128)
#define DN_TILES 176     // <=160 routed + 16 shared (K=2048)
#define ACT_SLOTS 24576  // sum pad128(cnt_e) (<=20448) + 4096 shared
#define TB_BLOCKS 8704   // 32*256 (wd) + 512 (wsd) 64x128 transpose tiles
#define TB_ROWS 544      // TB_BLOCKS / 16

typedef __bf16 bf16x8 __attribute__((ext_vector_type(8)));
typedef float  f32x4  __attribute__((ext_vector_type(4)));
static_assert(sizeof(bf16x8) == 16, "bf16x8 must be 16B");

// Workspace layout (bytes). Total = 486,885,376.
// po [ACT_SLOTS][H] bf16 (100.7 MB) ALIASES wgT (dead after gate_up).
#define OFF_CNT   ((size_t)0)            // cnt[34] int
#define OFF_NTGU  ((size_t)192)
#define OFF_NTDN  ((size_t)196)
#define OFF_BASE  ((size_t)256)          // base[34] int
#define OFF_TGU   ((size_t)512)          // tilesGU[192] uint
#define OFF_TDN   ((size_t)1280)         // tilesDN[176] uint
#define OFF_PAIRS ((size_t)2048)         // pairs[34][2048] uint = 278,528
#define OFF_XB    ((size_t)280576)       // xb [T,H] bf16 = 8,388,608
#define OFF_WGT   ((size_t)8669184)      // wgT [E][I][H] bf16 (po aliases)
#define OFF_PO    OFF_WGT
#define OFF_WUT   ((size_t)142886912)    // wuT [E][I][H] bf16
#define OFF_WSGT  ((size_t)277104640)    // wsgT [IS][H] bf16
#define OFF_WSUT  ((size_t)285493248)    // wsuT [IS][H] bf16
#define OFF_WDT   ((size_t)293881856)    // wdT [H][K_TOT] bf16
#define OFF_ACT   ((size_t)436488192)    // act [24576][1024] bf16 = 50,331,648
#define OFF_TSLOT ((size_t)486819840)    // tslot[T][8] uint = 65,536

__device__ __forceinline__ unsigned short f2bf(float f) {
  unsigned int u = __float_as_uint(f);
  u += 0x7fffu + ((u >> 16) & 1u);   // round-to-nearest-even
  return (unsigned short)(u >> 16);
}

__device__ __forceinline__ void gld16(const void* g, void* l) {
  __builtin_amdgcn_global_load_lds(
      (const __attribute__((address_space(1))) unsigned int*)g,
      (__attribute__((address_space(3))) unsigned int*)l, 16, 0, 0);
}

// ---------------------------------------------------------------------------
// Router: sigmoid(x @ gw^T); top-8; renorm; *2.5 -> pair lists + tslot + xb.
// ---------------------------------------------------------------------------
__global__ __launch_bounds__(256) void router_kernel(
    const float* __restrict__ x, const float* __restrict__ gw,
    int* __restrict__ cnt, unsigned int* __restrict__ pairs,
    unsigned int* __restrict__ tslot, unsigned short* __restrict__ xb)
{
  const int t = blockIdx.x;
  __shared__ float xs[H_DIM];
  __shared__ float sc[E_NUM];
  const float4* xr = (const float4*)(x + (long)t * H_DIM);
  for (int i = threadIdx.x; i < H_DIM / 4; i += 256) ((float4*)xs)[i] = xr[i];
  __syncthreads();
  {
    const int i0 = threadIdx.x * 8;
    ushort4 o1, o2;
    o1.x = f2bf(xs[i0 + 0]); o1.y = f2bf(xs[i0 + 1]);
    o1.z = f2bf(xs[i0 + 2]); o1.w = f2bf(xs[i0 + 3]);
    o2.x = f2bf(xs[i0 + 4]); o2.y = f2bf(xs[i0 + 5]);
    o2.z = f2bf(xs[i0 + 6]); o2.w = f2bf(xs[i0 + 7]);
    *(ushort4*)(xb + (long)t * H_DIM + i0) = o1;
    *(ushort4*)(xb + (long)t * H_DIM + i0 + 4) = o2;
  }
  const int e = threadIdx.x >> 3, p = threadIdx.x & 7;
  const float4* ga = (const float4*)(gw + (long)e * H_DIM);
  const float4* xa = (const float4*)xs;
  float s = 0.f;
  #pragma unroll 4
  for (int i = p * 64; i < p * 64 + 64; ++i) {
    float4 a = ga[i], b = xa[i];
    s += a.x * b.x + a.y * b.y + a.z * b.z + a.w * b.w;
  }
  s += __shfl_down(s, 4, 8);
  s += __shfl_down(s, 2, 8);
  s += __shfl_down(s, 1, 8);
  if (p == 0) sc[e] = 1.f / (1.f + expf(-s));
  __syncthreads();
  if (threadIdx.x == 0) {
    float v[E_NUM];
    #pragma unroll
    for (int i = 0; i < E_NUM; ++i) v[i] = sc[i];
    unsigned mask = 0; float sum = 0.f;
    int sel[8]; float wv[8];
    for (int k = 0; k < 8; ++k) {
      float best = -1.f; int bi = 0;
      for (int i = 0; i < E_NUM; ++i)
        if (!((mask >> i) & 1u) && v[i] > best) { best = v[i]; bi = i; }
      mask |= 1u << bi; sel[k] = bi; wv[k] = best; sum += best;
    }
    const float scale = 2.5f / (sum + 1e-20f);
    for (int k = 0; k < 8; ++k) {
      const int slot = atomicAdd(&cnt[sel[k]], 1);
      if (slot < SLOT_CAP) {
        const unsigned int w16 = (unsigned int)f2bf(wv[k] * scale);
        pairs[sel[k] * SLOT_CAP + slot] = (w16 << 16) | (unsigned int)t;
        tslot[t * 8 + k] = ((unsigned int)sel[k] << 16) | (unsigned int)slot;
      }
    }
  }
}

// ---------------------------------------------------------------------------
// Build tile lists (step 128) + pad128 act bases; fill shared pseudo pairs.
// ---------------------------------------------------------------------------
__global__ __launch_bounds__(256) void build_tiles_kernel(
    int* __restrict__ cnt, int* __restrict__ base,
    unsigned int* __restrict__ tgu, int* __restrict__ ntgu,
    unsigned int* __restrict__ tdn, int* __restrict__ ntdn,
    unsigned int* __restrict__ pairs)
{
  const int t = threadIdx.x;
  for (int s = t; s < T_TOK; s += 256) {
    const unsigned int pv = (0x3F80u << 16) | (unsigned int)s;  // w=1.0 bf16
    pairs[32 * SLOT_CAP + s] = pv;
    pairs[33 * SLOT_CAP + s] = pv;
  }
  if (t == 0) {
    cnt[32] = T_TOK; cnt[33] = T_TOK;
    int b = 0, ngu = 0, ndn = 0;
    for (int e = 0; e < NE_ALL; ++e) {
      const int c = (e < 32) ? cnt[e] : T_TOK;
      base[e] = b;
      for (int m0 = 0; m0 < c; m0 += 128) {
        tgu[ngu++] = ((unsigned int)e << 16) | (unsigned int)m0;
        if (e < 33) tdn[ndn++] = ((unsigned int)e << 16) | (unsigned int)m0;
      }
      b += (c + 127) & ~127;
    }
    *ntgu = ngu; *ntdn = ndn;
  }
}

// ---------------------------------------------------------------------------
// Standalone transpose+cvt (gate/up weights), 64(c) x 256(r) tiles — at its
// mixed-stream limit (~185us for this set).
// ---------------------------------------------------------------------------
struct TDescTable {
  const float* in[4];
  unsigned short* out[4];
  int C[4];
  int ldout[4];
  long in_bs[4];
  long out_bs[4];
  int nbx[4];
  int nbxy[4];
  int start[5];
};

__global__ __launch_bounds__(256) void transpose_A(TDescTable td)
{
  const int bid = blockIdx.x;
  int i = 0;
  while (i < 3 && bid >= td.start[i + 1]) ++i;
  const int local = bid - td.start[i];
  const int bz = local / td.nbxy[i];
  const int rem = local % td.nbxy[i];
  const int by = rem / td.nbx[i];
  const int bx = rem % td.nbx[i];
  const float* in = td.in[i] + (long)bz * td.in_bs[i];
  unsigned short* out = td.out[i] + (long)bz * td.out_bs[i];
  const int C = td.C[i], ldout = td.ldout[i];

  __shared__ unsigned short tile[64][258];
  const int c0 = bx * 64;
  const int r0 = by * 256;
  const int t = threadIdx.x;
  const int rl0 = t >> 4;
  const int cl0 = (t & 15) * 4;

  float4 v[16];
  #pragma unroll
  for (int p = 0; p < 16; ++p) {
    const int rl = p * 16 + rl0;
    v[p] = *(const float4*)(in + (long)(r0 + rl) * C + c0 + cl0);
  }
  __builtin_amdgcn_sched_barrier(0);
  #pragma unroll
  for (int p = 0; p < 16; ++p) {
    const int rl = p * 16 + rl0;
    tile[cl0 + 0][rl] = f2bf(v[p].x);
    tile[cl0 + 1][rl] = f2bf(v[p].y);
    tile[cl0 + 2][rl] = f2bf(v[p].z);
    tile[cl0 + 3][rl] = f2bf(v[p].w);
  }
  __syncthreads();
  const int cw = t >> 5;
  const int rw = (t & 31) * 8;
  #pragma unroll
  for (int q = 0; q < 8; ++q) {
    const int cl = q * 8 + cw;
    const char* src = (const char*)&tile[cl][rw];
    uint4 o;
    o.x = *(const unsigned int*)(src + 0);
    o.y = *(const unsigned int*)(src + 4);
    o.z = *(const unsigned int*)(src + 8);
    o.w = *(const unsigned int*)(src + 12);
    *(uint4*)(out + (long)(c0 + cl) * ldout + r0 + rw) = o;
  }
}

// ---------------------------------------------------------------------------
// FUSED: gate+up GEMM (round-12-proven geometry: 256 thr, 4 waves 2Mx2N,
// block 128x64, single-buf 32KB LDS, 5 blocks/CU) + down-weight transpose
// (64c x 128r tiles, 16.3KB LDS) interleaved in the SAME launch so the
// memory-bound transpose overlaps the MFMA-bound GEMM (m114 co-schedule).
// y%4!=0 -> transpose row; y%4==0 -> gate_up tile ti=y/4.
// ---------------------------------------------------------------------------
__global__ __launch_bounds__(256) void gate_up_tb_kernel(
    const unsigned short* __restrict__ xb,
    const unsigned short* __restrict__ bgT,
    const unsigned short* __restrict__ buT,
    const unsigned short* __restrict__ sgT,
    const unsigned short* __restrict__ suT,
    const int* __restrict__ cnt,
    const int* __restrict__ base,
    const unsigned int* __restrict__ pairs,
    const unsigned int* __restrict__ tiles,
    const int* __restrict__ ntp,
    unsigned short* __restrict__ act,
    const float* __restrict__ wd,
    const float* __restrict__ wsd,
    unsigned short* __restrict__ wdT)
{
  __shared__ unsigned short smem[16384];   // 32KB, shared by both paths
  const int y = blockIdx.y;

  if ((y & 3) != 0) {
    // ---- transpose path: wd / wsd -> wdT columns (64c x 128r tiles) ----
    const int tpRow = y - (y >> 2) - 1;
    if (tpRow >= TB_ROWS) return;
    const int bid = tpRow * 16 + blockIdx.x;
    const float* in;
    unsigned short* out;
    int by, bx;
    if (bid < 8192) {                       // wd: 32 experts x 256 blocks
      const int e = bid >> 8, rem = bid & 255;
      by = rem >> 5; bx = rem & 31;
      in = wd + (long)e * I_DIM * H_DIM;
      out = wdT + (long)e * I_DIM;
    } else {                                // wsd: 512 blocks
      const int b2 = bid - 8192;
      by = b2 >> 5; bx = b2 & 31;
      in = wsd;
      out = wdT + E_NUM * I_DIM;
    }
    const int c0 = bx * 64, r0 = by * 128;
    unsigned short (*tile)[130] = (unsigned short (*)[130])smem;
    const int t = threadIdx.x;
    const int rl0 = t >> 4;          // 0..15
    const int cl0 = (t & 15) * 4;
    float4 v[8];
    #pragma unroll
    for (int p = 0; p < 8; ++p) {
      const int rl = p * 16 + rl0;
      v[p] = *(const float4*)(in + (long)(r0 + rl) * H_DIM + c0 + cl0);
    }
    __builtin_amdgcn_sched_barrier(0);
    #pragma unroll
    for (int p = 0; p < 8; ++p) {
      const int rl = p * 16 + rl0;
      tile[cl0 + 0][rl] = f2bf(v[p].x);
      tile[cl0 + 1][rl] = f2bf(v[p].y);
      tile[cl0 + 2][rl] = f2bf(v[p].z);
      tile[cl0 + 3][rl] = f2bf(v[p].w);
    }
    __syncthreads();
    const int cw = t >> 4;           // 0..15
    const int rw = (t & 15) * 8;     // 0..120
    #pragma unroll
    for (int q = 0; q < 4; ++q) {
      const int cl = q * 16 + cw;
      const char* src = (const char*)&tile[cl][rw];
      uint4 o;
      o.x = *(const unsigned int*)(src + 0);
      o.y = *(const unsigned int*)(src + 4);
      o.z = *(const unsigned int*)(src + 8);
      o.w = *(const unsigned int*)(src + 12);
      *(uint4*)(out + (long)(c0 + cl) * K_TOT + r0 + rw) = o;
    }
    return;
  }

  // ---- gate_up path (round-12 structure) ----
  const int ti = y >> 2;
  if (ti >= *ntp) return;
  const unsigned int tile = tiles[ti];
  const int e  = (int)(tile >> 16);
  const int m0 = (int)(tile & 0xFFFFu);
  const int cnte = cnt[e];
  const int be = base[e];
  const int n0 = blockIdx.x * 64;
  const long panel = (long)I_DIM * H_DIM;
  const unsigned short* Bg =
      ((e < 32) ? bgT + e * panel : sgT + (e - 32) * panel) + (long)n0 * H_DIM;
  const unsigned short* Bu =
      ((e < 32) ? buT + e * panel : suT + (e - 32) * panel) + (long)n0 * H_DIM;

  unsigned short* sA  = smem;              // 128*64
  unsigned short* sBg = smem + 8192;       // 64*64
  unsigned short* sBu = smem + 12288;      // 64*64

  const int tid = threadIdx.x;
  const int lane = tid & 63;
  const int wid = tid >> 6;
  const int wm = wid >> 1, wn = wid & 1;
  const int l15 = lane & 15;
  const int lk  = (lane >> 4) * 8;
  const int srow = tid >> 3;                       // 0..31
  const int scol = (tid & 7) * 8;
  const int scolsw = (((tid & 7) ^ (srow & 7))) * 8;
  const int ksw = (l15 & 7) << 3;

  const unsigned short* asrc[4];
  #pragma unroll
  for (int r = 0; r < 4; ++r) {
    const int slot = m0 + r * 32 + srow;
    const unsigned int pr = (slot < cnte) ? pairs[e * SLOT_CAP + slot] : 0u;
    asrc[r] = xb + (long)(pr & 0xFFFFu) * H_DIM + scolsw;
  }

  const f32x4 fz = {0.f, 0.f, 0.f, 0.f};
  f32x4 accg[4][2], accu[4][2];
  #pragma unroll
  for (int i = 0; i < 4; ++i)
    #pragma unroll
    for (int j = 0; j < 2; ++j) { accg[i][j] = fz; accu[i][j] = fz; }

  for (int k0 = 0; k0 < H_DIM; k0 += 64) {
    #pragma unroll
    for (int r = 0; r < 4; ++r)
      gld16(asrc[r] + k0, sA + (r * 32 + srow) * 64 + scol);
    #pragma unroll
    for (int r = 0; r < 2; ++r) {
      gld16(Bg + (long)(r * 32 + srow) * H_DIM + k0 + scolsw,
            sBg + (r * 32 + srow) * 64 + scol);
      gld16(Bu + (long)(r * 32 + srow) * H_DIM + k0 + scolsw,
            sBu + (r * 32 + srow) * 64 + scol);
    }
    __syncthreads();
    __builtin_amdgcn_s_setprio(1);
    #pragma unroll
    for (int kk = 0; kk < 2; ++kk) {
      const int ko = kk * 32 + lk;
      bf16x8 a[4], g[2], u[2];
      #pragma unroll
      for (int mi = 0; mi < 4; ++mi)
        a[mi] = *(const bf16x8*)(sA + (wm * 64 + mi * 16 + l15) * 64 + (ko ^ ksw));
      #pragma unroll
      for (int ni = 0; ni < 2; ++ni) {
        g[ni] = *(const bf16x8*)(sBg + (wn * 32 + ni * 16 + l15) * 64 + (ko ^ ksw));
        u[ni] = *(const bf16x8*)(sBu + (wn * 32 + ni * 16 + l15) * 64 + (ko ^ ksw));
      }
      #pragma unroll
      for (int mi = 0; mi < 4; ++mi)
        #pragma unroll
        for (int ni = 0; ni < 2; ++ni) {
          accg[mi][ni] = __builtin_amdgcn_mfma_f32_16x16x32_bf16(a[mi], g[ni], accg[mi][ni], 0, 0, 0);
          accu[mi][ni] = __builtin_amdgcn_mfma_f32_16x16x32_bf16(a[mi], u[ni], accu[mi][ni], 0, 0, 0);
        }
    }
    __builtin_amdgcn_s_setprio(0);
    __syncthreads();
  }

  const int colb = n0 + wn * 32;
  #pragma unroll
  for (int mi = 0; mi < 4; ++mi) {
    #pragma unroll
    for (int r = 0; r < 4; ++r) {
      const int slot = m0 + wm * 64 + mi * 16 + (lane >> 4) * 4 + r;
      if (slot < cnte) {
        const unsigned int pr = pairs[e * SLOT_CAP + slot];
        const float w = __uint_as_float(pr & 0xFFFF0000u);
        #pragma unroll
        for (int ni = 0; ni < 2; ++ni) {
          const float gv = accg[mi][ni][r];
          const float uv = accu[mi][ni][r];
          const float sv = (gv / (1.f + expf(-gv))) * uv * w;
          act[((long)(be + slot)) * I_DIM + colb + ni * 16 + l15] = f2bf(sv);
        }
      }
    }
  }
}

// ---------------------------------------------------------------------------
// Down GEMM (round-12 geometry): 256 thr, 4 waves (2Mx2N), wave tile 64x64,
// block 128(M)x128(N), single-buf 32KB LDS, 2-barrier loop. e=32 runs K=2048.
// Plain bf16 stores to po (combine kernel sums).
// ---------------------------------------------------------------------------
__global__ __launch_bounds__(256) void down_moe_kernel(
    const unsigned short* __restrict__ act,
    const unsigned short* __restrict__ wdT,
    const int* __restrict__ cnt,
    const int* __restrict__ base,
    const unsigned int* __restrict__ tiles,
    const int* __restrict__ ntp,
    unsigned short* __restrict__ po)
{
  const int ti = blockIdx.y;
  if (ti >= *ntp) return;
  const unsigned int tile = tiles[ti];
  const int e  = (int)(tile >> 16);
  const int m0 = (int)(tile & 0xFFFFu);
  const int cnte = cnt[e];
  const int be = base[e];
  const int n0 = blockIdx.x * 128;
  const unsigned short* A = act + ((long)be + m0) * I_DIM;
  const unsigned short* B = wdT + (long)n0 * K_TOT + (long)e * I_DIM;
  const int nk = (e == 32) ? 32 : 16;

  __shared__ unsigned short sA[128 * 64];
  __shared__ unsigned short sB[128 * 64];

  const int tid = threadIdx.x;
  const int lane = tid & 63;
  const int wid = tid >> 6;
  const int wm = wid >> 1, wn = wid & 1;
  const int l15 = lane & 15;
  const int lk  = (lane >> 4) * 8;
  const int srow = tid >> 3;
  const int scol = (tid & 7) * 8;
  const int scolsw = (((tid & 7) ^ (srow & 7))) * 8;
  const int ksw = (l15 & 7) << 3;

  const f32x4 fz = {0.f, 0.f, 0.f, 0.f};
  f32x4 acc[4][4];
  #pragma unroll
  for (int i = 0; i < 4; ++i)
    #pragma unroll
    for (int j = 0; j < 4; ++j) acc[i][j] = fz;

  for (int t = 0; t < nk; ++t) {
    const int k0 = t * 64;
    const long koff = (long)(k0 & 1023) + (long)(k0 >> 10) * (2048L * 1024L);
    #pragma unroll
    for (int r = 0; r < 4; ++r)
      gld16(A + (long)(r * 32 + srow) * I_DIM + koff + scolsw,
            sA + (r * 32 + srow) * 64 + scol);
    #pragma unroll
    for (int r = 0; r < 4; ++r)
      gld16(B + (long)(r * 32 + srow) * K_TOT + k0 + scolsw,
            sB + (r * 32 + srow) * 64 + scol);
    __syncthreads();
    __builtin_amdgcn_s_setprio(1);
    #pragma unroll
    for (int kk = 0; kk < 2; ++kk) {
      const int ko = kk * 32 + lk;
      bf16x8 a[4], b[4];
      #pragma unroll
      for (int mi = 0; mi < 4; ++mi)
        a[mi] = *(const bf16x8*)(sA + (wm * 64 + mi * 16 + l15) * 64 + (ko ^ ksw));
      #pragma unroll
      for (int ni = 0; ni < 4; ++ni)
        b[ni] = *(const bf16x8*)(sB + (wn * 64 + ni * 16 + l15) * 64 + (ko ^ ksw));
      #pragma unroll
      for (int mi = 0; mi < 4; ++mi)
        #pragma unroll
        for (int ni = 0; ni < 4; ++ni)
          acc[mi][ni] = __builtin_amdgcn_mfma_f32_16x16x32_bf16(a[mi], b[ni], acc[mi][ni], 0, 0, 0);
    }
    __builtin_amdgcn_s_setprio(0);
    __syncthreads();
  }

  #pragma unroll
  for (int mi = 0; mi < 4; ++mi) {
    #pragma unroll
    for (int r = 0; r < 4; ++r) {
      const int slot = m0 + wm * 64 + mi * 16 + (lane >> 4) * 4 + r;
      if (slot < cnte) {
        unsigned short* pr = po + (long)(be + slot) * H_DIM + n0 + wn * 64;
        #pragma unroll
        for (int ni = 0; ni < 4; ++ni)
          pr[ni * 16 + l15] = f2bf(acc[mi][ni][r]);
      }
    }
  }
}

// ---------------------------------------------------------------------------
// Combine: out[t][h] = sum of token's 8 routed partial rows + shared row.
// ---------------------------------------------------------------------------
__global__ __launch_bounds__(256) void combine_kernel(
    const unsigned short* __restrict__ po,
    const int* __restrict__ base,
    const unsigned int* __restrict__ tslot,
    float* __restrict__ out)
{
  const int t = blockIdx.x;
  __shared__ int rows[9];
  if (threadIdx.x < 8) {
    const unsigned int pr = tslot[t * 8 + threadIdx.x];
    rows[threadIdx.x] = base[pr >> 16] + (int)(pr & 0xFFFFu);
  }
  if (threadIdx.x == 8) rows[8] = base[32] + t;
  __syncthreads();
  const int col = threadIdx.x * 8;
  float s[8];
  #pragma unroll
  for (int j = 0; j < 8; ++j) s[j] = 0.f;
  #pragma unroll
  for (int k = 0; k < 9; ++k) {
    const ushort4* p = (const ushort4*)(po + (long)rows[k] * H_DIM + col);
    const ushort4 v0 = p[0], v1 = p[1];
    s[0] += __uint_as_float((unsigned int)v0.x << 16);
    s[1] += __uint_as_float((unsigned int)v0.y << 16);
    s[2] += __uint_as_float((unsigned int)v0.z << 16);
    s[3] += __uint_as_float((unsigned int)v0.w << 16);
    s[4] += __uint_as_float((unsigned int)v1.x << 16);
    s[5] += __uint_as_float((unsigned int)v1.y << 16);
    s[6] += __uint_as_float((unsigned int)v1.z << 16);
    s[7] += __uint_as_float((unsigned int)v1.w << 16);
  }
  float4 o0 = {s[0], s[1], s[2], s[3]};
  float4 o1 = {s[4], s[5], s[6], s[7]};
  *(float4*)(out + (long)t * H_DIM + col) = o0;
  *(float4*)(out + (long)t * H_DIM + col + 4) = o1;
}

// ---------------------------------------------------------------------------
extern "C" void kernel_launch(void* const* d_in, const int* in_sizes, int n_in,
                              void* d_out, int out_size, void* d_ws, size_t ws_size,
                              hipStream_t stream) {
  (void)in_sizes; (void)n_in; (void)out_size; (void)ws_size;
  const float* x   = (const float*)d_in[0];
  const float* gw  = (const float*)d_in[1];
  const float* wg  = (const float*)d_in[2];
  const float* wu  = (const float*)d_in[3];
  const float* wd  = (const float*)d_in[4];
  const float* wsg = (const float*)d_in[5];
  const float* wsu = (const float*)d_in[6];
  const float* wsd = (const float*)d_in[7];
  float* out = (float*)d_out;
  char* ws = (char*)d_ws;

  int*            cnt   = (int*)(ws + OFF_CNT);
  int*            ntgu  = (int*)(ws + OFF_NTGU);
  int*            ntdn  = (int*)(ws + OFF_NTDN);
  int*            basep = (int*)(ws + OFF_BASE);
  unsigned int*   tgu   = (unsigned int*)(ws + OFF_TGU);
  unsigned int*   tdn   = (unsigned int*)(ws + OFF_TDN);
  unsigned int*   pairs = (unsigned int*)(ws + OFF_PAIRS);
  unsigned int*   tslot = (unsigned int*)(ws + OFF_TSLOT);
  unsigned short* xb    = (unsigned short*)(ws + OFF_XB);
  unsigned short* wgT   = (unsigned short*)(ws + OFF_WGT);
  unsigned short* wuT   = (unsigned short*)(ws + OFF_WUT);
  unsigned short* wsgT  = (unsigned short*)(ws + OFF_WSGT);
  unsigned short* wsuT  = (unsigned short*)(ws + OFF_WSUT);
  unsigned short* wdT   = (unsigned short*)(ws + OFF_WDT);
  unsigned short* actb  = (unsigned short*)(ws + OFF_ACT);
  unsigned short* pob   = (unsigned short*)(ws + OFF_PO);   // aliases wgT

  hipMemsetAsync(ws + OFF_CNT, 0, 256, stream);

  router_kernel<<<T_TOK, 256, 0, stream>>>(x, gw, cnt, pairs, tslot, xb);
  build_tiles_kernel<<<1, 256, 0, stream>>>(cnt, basep, tgu, ntgu, tdn, ntdn,
                                            pairs);

  // transpose A: gate/up weights
  TDescTable ta;
  ta.in[0] = wg;  ta.out[0] = wgT;  ta.C[0] = I_DIM;  ta.ldout[0] = H_DIM;
  ta.in_bs[0] = (long)H_DIM * I_DIM; ta.out_bs[0] = (long)I_DIM * H_DIM;
  ta.nbx[0] = I_DIM / 64; ta.nbxy[0] = (I_DIM / 64) * (H_DIM / 256);
  ta.in[1] = wu;  ta.out[1] = wuT;  ta.C[1] = I_DIM;  ta.ldout[1] = H_DIM;
  ta.in_bs[1] = (long)H_DIM * I_DIM; ta.out_bs[1] = (long)I_DIM * H_DIM;
  ta.nbx[1] = I_DIM / 64; ta.nbxy[1] = (I_DIM / 64) * (H_DIM / 256);
  ta.in[2] = wsg; ta.out[2] = wsgT; ta.C[2] = IS_DIM; ta.ldout[2] = H_DIM;
  ta.in_bs[2] = 0; ta.out_bs[2] = 0;
  ta.nbx[2] = IS_DIM / 64; ta.nbxy[2] = (IS_DIM / 64) * (H_DIM / 256);
  ta.in[3] = wsu; ta.out[3] = wsuT; ta.C[3] = IS_DIM; ta.ldout[3] = H_DIM;
  ta.in_bs[3] = 0; ta.out_bs[3] = 0;
  ta.nbx[3] = IS_DIM / 64; ta.nbxy[3] = (IS_DIM / 64) * (H_DIM / 256);
  ta.start[0] = 0;
  ta.start[1] = ta.start[0] + ta.nbxy[0] * E_NUM;
  ta.start[2] = ta.start[1] + ta.nbxy[1] * E_NUM;
  ta.start[3] = ta.start[2] + ta.nbxy[2];
  ta.start[4] = ta.start[3] + ta.nbxy[3];
  transpose_A<<<ta.start[4], 256, 0, stream>>>(ta);

  // FUSED gate+up GEMM + down-weight transpose (overlapped in one launch)
  gate_up_tb_kernel<<<dim3(16, 4 * GU_TILES), 256, 0, stream>>>(
      xb, wgT, wuT, wsgT, wsuT, cnt, basep, pairs, tgu, ntgu, actb,
      wd, wsd, wdT);

  // down (routed K=1024, shared K=2048) -> plain-store partials (po aliases
  // wgT, dead after gate_up)
  down_moe_kernel<<<dim3(16, DN_TILES), 256, 0, stream>>>(
      actb, wdT, cnt, basep, tdn, ntdn, pob);

  // gather-combine: 9 partial rows per token -> out
  combine_kernel<<<T_TOK, 256, 0, stream>>>(pob, basep, tslot, out);
}

// Round 16
// 747.897 us; speedup vs baseline: 1.4196x; 1.1600x over previous
//
#include <hip/hip_runtime.h>

// Problem dims (fixed by the reference)
#define T_TOK 2048      // B*S tokens
#define H_DIM 2048
#define E_NUM 32
#define I_DIM 1024
#define IS_DIM 2048
#define K_TOT (E_NUM * I_DIM + IS_DIM)   // 34816
#define SLOT_CAP 2048
#define NE_ALL 34        // 32 routed + 2 shared pseudo-experts
#define GU_TILES 192     // <=160 routed + 32 shared (step 128)
#define DN_TILES 176     // <=160 routed + 16 shared (K=2048)
#define ACT_SLOTS 24576  // sum pad128(cnt_e) (<=20448) + 4096 shared

typedef __bf16 bf16x8 __attribute__((ext_vector_type(8)));
typedef float  f32x4  __attribute__((ext_vector_type(4)));
static_assert(sizeof(bf16x8) == 16, "bf16x8 must be 16B");

// Workspace layout (bytes). Total = 486,885,376.
// po [ACT_SLOTS][H] bf16 (100.7 MB) ALIASES wgT (dead after gate_up).
#define OFF_CNT   ((size_t)0)            // cnt[34] int
#define OFF_NTGU  ((size_t)192)
#define OFF_NTDN  ((size_t)196)
#define OFF_BASE  ((size_t)256)          // base[34] int
#define OFF_TGU   ((size_t)512)          // tilesGU[192] uint
#define OFF_TDN   ((size_t)1280)         // tilesDN[176] uint
#define OFF_PAIRS ((size_t)2048)         // pairs[34][2048] uint = 278,528
#define OFF_XB    ((size_t)280576)       // xb [T,H] bf16 = 8,388,608
#define OFF_WGT   ((size_t)8669184)      // wgT [E][I][H] bf16 (po aliases)
#define OFF_PO    OFF_WGT
#define OFF_WUT   ((size_t)142886912)    // wuT [E][I][H] bf16
#define OFF_WSGT  ((size_t)277104640)    // wsgT [IS][H] bf16
#define OFF_WSUT  ((size_t)285493248)    // wsuT [IS][H] bf16
#define OFF_WDT   ((size_t)293881856)    // wdT [H][K_TOT] bf16
#define OFF_ACT   ((size_t)436488192)    // act [24576][1024] bf16 = 50,331,648
#define OFF_TSLOT ((size_t)486819840)    // tslot[T][8] uint = 65,536

__device__ __forceinline__ unsigned short f2bf(float f) {
  unsigned int u = __float_as_uint(f);
  u += 0x7fffu + ((u >> 16) & 1u);   // round-to-nearest-even
  return (unsigned short)(u >> 16);
}

__device__ __forceinline__ void gld16(const void* g, void* l) {
  __builtin_amdgcn_global_load_lds(
      (const __attribute__((address_space(1))) unsigned int*)g,
      (__attribute__((address_space(3))) unsigned int*)l, 16, 0, 0);
}

// ---------------------------------------------------------------------------
// Router: sigmoid(x @ gw^T); top-8; renorm; *2.5 -> pair lists + tslot + xb.
// ---------------------------------------------------------------------------
__global__ __launch_bounds__(256) void router_kernel(
    const float* __restrict__ x, const float* __restrict__ gw,
    int* __restrict__ cnt, unsigned int* __restrict__ pairs,
    unsigned int* __restrict__ tslot, unsigned short* __restrict__ xb)
{
  const int t = blockIdx.x;
  __shared__ float xs[H_DIM];
  __shared__ float sc[E_NUM];
  const float4* xr = (const float4*)(x + (long)t * H_DIM);
  for (int i = threadIdx.x; i < H_DIM / 4; i += 256) ((float4*)xs)[i] = xr[i];
  __syncthreads();
  {
    const int i0 = threadIdx.x * 8;
    ushort4 o1, o2;
    o1.x = f2bf(xs[i0 + 0]); o1.y = f2bf(xs[i0 + 1]);
    o1.z = f2bf(xs[i0 + 2]); o1.w = f2bf(xs[i0 + 3]);
    o2.x = f2bf(xs[i0 + 4]); o2.y = f2bf(xs[i0 + 5]);
    o2.z = f2bf(xs[i0 + 6]); o2.w = f2bf(xs[i0 + 7]);
    *(ushort4*)(xb + (long)t * H_DIM + i0) = o1;
    *(ushort4*)(xb + (long)t * H_DIM + i0 + 4) = o2;
  }
  const int e = threadIdx.x >> 3, p = threadIdx.x & 7;
  const float4* ga = (const float4*)(gw + (long)e * H_DIM);
  const float4* xa = (const float4*)xs;
  float s = 0.f;
  #pragma unroll 4
  for (int i = p * 64; i < p * 64 + 64; ++i) {
    float4 a = ga[i], b = xa[i];
    s += a.x * b.x + a.y * b.y + a.z * b.z + a.w * b.w;
  }
  s += __shfl_down(s, 4, 8);
  s += __shfl_down(s, 2, 8);
  s += __shfl_down(s, 1, 8);
  if (p == 0) sc[e] = 1.f / (1.f + expf(-s));
  __syncthreads();
  if (threadIdx.x == 0) {
    float v[E_NUM];
    #pragma unroll
    for (int i = 0; i < E_NUM; ++i) v[i] = sc[i];
    unsigned mask = 0; float sum = 0.f;
    int sel[8]; float wv[8];
    for (int k = 0; k < 8; ++k) {
      float best = -1.f; int bi = 0;
      for (int i = 0; i < E_NUM; ++i)
        if (!((mask >> i) & 1u) && v[i] > best) { best = v[i]; bi = i; }
      mask |= 1u << bi; sel[k] = bi; wv[k] = best; sum += best;
    }
    const float scale = 2.5f / (sum + 1e-20f);
    for (int k = 0; k < 8; ++k) {
      const int slot = atomicAdd(&cnt[sel[k]], 1);
      if (slot < SLOT_CAP) {
        const unsigned int w16 = (unsigned int)f2bf(wv[k] * scale);
        pairs[sel[k] * SLOT_CAP + slot] = (w16 << 16) | (unsigned int)t;
        tslot[t * 8 + k] = ((unsigned int)sel[k] << 16) | (unsigned int)slot;
      }
    }
  }
}

// ---------------------------------------------------------------------------
// Build tile lists (step 128) + pad128 act bases; fill shared pseudo pairs.
// ---------------------------------------------------------------------------
__global__ __launch_bounds__(256) void build_tiles_kernel(
    int* __restrict__ cnt, int* __restrict__ base,
    unsigned int* __restrict__ tgu, int* __restrict__ ntgu,
    unsigned int* __restrict__ tdn, int* __restrict__ ntdn,
    unsigned int* __restrict__ pairs)
{
  const int t = threadIdx.x;
  for (int s = t; s < T_TOK; s += 256) {
    const unsigned int pv = (0x3F80u << 16) | (unsigned int)s;  // w=1.0 bf16
    pairs[32 * SLOT_CAP + s] = pv;
    pairs[33 * SLOT_CAP + s] = pv;
  }
  if (t == 0) {
    cnt[32] = T_TOK; cnt[33] = T_TOK;
    int b = 0, ngu = 0, ndn = 0;
    for (int e = 0; e < NE_ALL; ++e) {
      const int c = (e < 32) ? cnt[e] : T_TOK;
      base[e] = b;
      for (int m0 = 0; m0 < c; m0 += 128) {
        tgu[ngu++] = ((unsigned int)e << 16) | (unsigned int)m0;
        if (e < 33) tdn[ndn++] = ((unsigned int)e << 16) | (unsigned int)m0;
      }
      b += (c + 127) & ~127;
    }
    *ntgu = ngu; *ntdn = ndn;
  }
}

// ---------------------------------------------------------------------------
// Transpose+cvt, 64(c) x 256(r) tiles — at its mixed-stream limit (~274us
// for all 6 tensors, 3 structural variants identical). Single fused launch.
// ---------------------------------------------------------------------------
struct TDescTable {
  const float* in[6];
  unsigned short* out[6];
  int C[6];
  int ldout[6];
  long in_bs[6];
  long out_bs[6];
  int nbx[6];
  int nbxy[6];
  int start[7];
};

__global__ __launch_bounds__(256) void transpose_fused(TDescTable td)
{
  const int bid = blockIdx.x;
  int i = 0;
  while (i < 5 && bid >= td.start[i + 1]) ++i;
  const int local = bid - td.start[i];
  const int bz = local / td.nbxy[i];
  const int rem = local % td.nbxy[i];
  const int by = rem / td.nbx[i];
  const int bx = rem % td.nbx[i];
  const float* in = td.in[i] + (long)bz * td.in_bs[i];
  unsigned short* out = td.out[i] + (long)bz * td.out_bs[i];
  const int C = td.C[i], ldout = td.ldout[i];

  __shared__ unsigned short tile[64][258];
  const int c0 = bx * 64;
  const int r0 = by * 256;
  const int t = threadIdx.x;
  const int rl0 = t >> 4;
  const int cl0 = (t & 15) * 4;

  float4 v[16];
  #pragma unroll
  for (int p = 0; p < 16; ++p) {
    const int rl = p * 16 + rl0;
    v[p] = *(const float4*)(in + (long)(r0 + rl) * C + c0 + cl0);
  }
  __builtin_amdgcn_sched_barrier(0);
  #pragma unroll
  for (int p = 0; p < 16; ++p) {
    const int rl = p * 16 + rl0;
    tile[cl0 + 0][rl] = f2bf(v[p].x);
    tile[cl0 + 1][rl] = f2bf(v[p].y);
    tile[cl0 + 2][rl] = f2bf(v[p].z);
    tile[cl0 + 3][rl] = f2bf(v[p].w);
  }
  __syncthreads();
  const int cw = t >> 5;
  const int rw = (t & 31) * 8;
  #pragma unroll
  for (int q = 0; q < 8; ++q) {
    const int cl = q * 8 + cw;
    const char* src = (const char*)&tile[cl][rw];
    uint4 o;
    o.x = *(const unsigned int*)(src + 0);
    o.y = *(const unsigned int*)(src + 4);
    o.z = *(const unsigned int*)(src + 8);
    o.w = *(const unsigned int*)(src + 12);
    *(uint4*)(out + (long)(c0 + cl) * ldout + r0 + rw) = o;
  }
}

// ---------------------------------------------------------------------------
// Gate+up GEMM: 512 thr (8 waves, 2Mx4N), block 128(slots) x 128(n), BK=64,
// per-wave tile 64x32 (the proven round-12 inner loop, unchanged), single-buf
// 48KB LDS (3 blocks/CU = 24 waves), 2-barrier K-loop, XOR-swizzled LDS,
// gathered A rows, setprio around MFMA. BN 64->128 halves A refetch and
// doubles MFMA per barrier drain.
// ---------------------------------------------------------------------------
__global__ __launch_bounds__(512) void gate_up_moe_kernel(
    const unsigned short* __restrict__ xb,
    const unsigned short* __restrict__ bgT,
    const unsigned short* __restrict__ buT,
    const unsigned short* __restrict__ sgT,
    const unsigned short* __restrict__ suT,
    const int* __restrict__ cnt,
    const int* __restrict__ base,
    const unsigned int* __restrict__ pairs,
    const unsigned int* __restrict__ tiles,
    const int* __restrict__ ntp,
    unsigned short* __restrict__ act)
{
  const int ti = blockIdx.y;
  if (ti >= *ntp) return;
  const unsigned int tile = tiles[ti];
  const int e  = (int)(tile >> 16);
  const int m0 = (int)(tile & 0xFFFFu);
  const int cnte = cnt[e];
  const int be = base[e];
  const int n0 = blockIdx.x * 128;
  const long panel = (long)I_DIM * H_DIM;
  const unsigned short* Bg =
      ((e < 32) ? bgT + e * panel : sgT + (e - 32) * panel) + (long)n0 * H_DIM;
  const unsigned short* Bu =
      ((e < 32) ? buT + e * panel : suT + (e - 32) * panel) + (long)n0 * H_DIM;

  __shared__ unsigned short sA[128 * 64];    // 16KB
  __shared__ unsigned short sBg[128 * 64];   // 16KB
  __shared__ unsigned short sBu[128 * 64];   // 16KB

  const int tid = threadIdx.x;
  const int lane = tid & 63;
  const int wid = tid >> 6;            // 0..7
  const int wm = wid >> 2, wn = wid & 3;
  const int l15 = lane & 15;
  const int lk  = (lane >> 4) * 8;
  const int srow = tid >> 3;           // 0..63
  const int scol = (tid & 7) * 8;
  const int scolsw = (((tid & 7) ^ (srow & 7))) * 8;
  const int ksw = (l15 & 7) << 3;

  const unsigned short* asrc[2];
  #pragma unroll
  for (int r = 0; r < 2; ++r) {
    const int slot = m0 + r * 64 + srow;
    const unsigned int pr = (slot < cnte) ? pairs[e * SLOT_CAP + slot] : 0u;
    asrc[r] = xb + (long)(pr & 0xFFFFu) * H_DIM + scolsw;
  }

  const f32x4 fz = {0.f, 0.f, 0.f, 0.f};
  f32x4 accg[4][2], accu[4][2];
  #pragma unroll
  for (int i = 0; i < 4; ++i)
    #pragma unroll
    for (int j = 0; j < 2; ++j) { accg[i][j] = fz; accu[i][j] = fz; }

  for (int k0 = 0; k0 < H_DIM; k0 += 64) {
    #pragma unroll
    for (int r = 0; r < 2; ++r) {
      gld16(asrc[r] + k0, sA + (r * 64 + srow) * 64 + scol);
      gld16(Bg + (long)(r * 64 + srow) * H_DIM + k0 + scolsw,
            sBg + (r * 64 + srow) * 64 + scol);
      gld16(Bu + (long)(r * 64 + srow) * H_DIM + k0 + scolsw,
            sBu + (r * 64 + srow) * 64 + scol);
    }
    __syncthreads();
    __builtin_amdgcn_s_setprio(1);
    #pragma unroll
    for (int kk = 0; kk < 2; ++kk) {
      const int ko = kk * 32 + lk;
      bf16x8 a[4], g[2], u[2];
      #pragma unroll
      for (int mi = 0; mi < 4; ++mi)
        a[mi] = *(const bf16x8*)(sA + (wm * 64 + mi * 16 + l15) * 64 + (ko ^ ksw));
      #pragma unroll
      for (int ni = 0; ni < 2; ++ni) {
        g[ni] = *(const bf16x8*)(sBg + (wn * 32 + ni * 16 + l15) * 64 + (ko ^ ksw));
        u[ni] = *(const bf16x8*)(sBu + (wn * 32 + ni * 16 + l15) * 64 + (ko ^ ksw));
      }
      #pragma unroll
      for (int mi = 0; mi < 4; ++mi)
        #pragma unroll
        for (int ni = 0; ni < 2; ++ni) {
          accg[mi][ni] = __builtin_amdgcn_mfma_f32_16x16x32_bf16(a[mi], g[ni], accg[mi][ni], 0, 0, 0);
          accu[mi][ni] = __builtin_amdgcn_mfma_f32_16x16x32_bf16(a[mi], u[ni], accu[mi][ni], 0, 0, 0);
        }
    }
    __builtin_amdgcn_s_setprio(0);
    __syncthreads();
  }

  const int colb = n0 + wn * 32;
  #pragma unroll
  for (int mi = 0; mi < 4; ++mi) {
    #pragma unroll
    for (int r = 0; r < 4; ++r) {
      const int slot = m0 + wm * 64 + mi * 16 + (lane >> 4) * 4 + r;
      if (slot < cnte) {
        const unsigned int pr = pairs[e * SLOT_CAP + slot];
        const float w = __uint_as_float(pr & 0xFFFF0000u);
        #pragma unroll
        for (int ni = 0; ni < 2; ++ni) {
          const float gv = accg[mi][ni][r];
          const float uv = accu[mi][ni][r];
          const float sv = (gv / (1.f + expf(-gv))) * uv * w;
          act[((long)(be + slot)) * I_DIM + colb + ni * 16 + l15] = f2bf(sv);
        }
      }
    }
  }
}

// ---------------------------------------------------------------------------
// Down GEMM (round-12 geometry, unchanged): 256 thr, 4 waves (2Mx2N), wave
// tile 64x64, block 128x128, single-buf 32KB LDS, 2-barrier loop. e=32 runs
// K=2048 spanning both shared act panels. Plain bf16 stores to po.
// ---------------------------------------------------------------------------
__global__ __launch_bounds__(256) void down_moe_kernel(
    const unsigned short* __restrict__ act,
    const unsigned short* __restrict__ wdT,
    const int* __restrict__ cnt,
    const int* __restrict__ base,
    const unsigned int* __restrict__ tiles,
    const int* __restrict__ ntp,
    unsigned short* __restrict__ po)
{
  const int ti = blockIdx.y;
  if (ti >= *ntp) return;
  const unsigned int tile = tiles[ti];
  const int e  = (int)(tile >> 16);
  const int m0 = (int)(tile & 0xFFFFu);
  const int cnte = cnt[e];
  const int be = base[e];
  const int n0 = blockIdx.x * 128;
  const unsigned short* A = act + ((long)be + m0) * I_DIM;
  const unsigned short* B = wdT + (long)n0 * K_TOT + (long)e * I_DIM;
  const int nk = (e == 32) ? 32 : 16;

  __shared__ unsigned short sA[128 * 64];
  __shared__ unsigned short sB[128 * 64];

  const int tid = threadIdx.x;
  const int lane = tid & 63;
  const int wid = tid >> 6;
  const int wm = wid >> 1, wn = wid & 1;
  const int l15 = lane & 15;
  const int lk  = (lane >> 4) * 8;
  const int srow = tid >> 3;
  const int scol = (tid & 7) * 8;
  const int scolsw = (((tid & 7) ^ (srow & 7))) * 8;
  const int ksw = (l15 & 7) << 3;

  const f32x4 fz = {0.f, 0.f, 0.f, 0.f};
  f32x4 acc[4][4];
  #pragma unroll
  for (int i = 0; i < 4; ++i)
    #pragma unroll
    for (int j = 0; j < 4; ++j) acc[i][j] = fz;

  for (int t = 0; t < nk; ++t) {
    const int k0 = t * 64;
    const long koff = (long)(k0 & 1023) + (long)(k0 >> 10) * (2048L * 1024L);
    #pragma unroll
    for (int r = 0; r < 4; ++r)
      gld16(A + (long)(r * 32 + srow) * I_DIM + koff + scolsw,
            sA + (r * 32 + srow) * 64 + scol);
    #pragma unroll
    for (int r = 0; r < 4; ++r)
      gld16(B + (long)(r * 32 + srow) * K_TOT + k0 + scolsw,
            sB + (r * 32 + srow) * 64 + scol);
    __syncthreads();
    __builtin_amdgcn_s_setprio(1);
    #pragma unroll
    for (int kk = 0; kk < 2; ++kk) {
      const int ko = kk * 32 + lk;
      bf16x8 a[4], b[4];
      #pragma unroll
      for (int mi = 0; mi < 4; ++mi)
        a[mi] = *(const bf16x8*)(sA + (wm * 64 + mi * 16 + l15) * 64 + (ko ^ ksw));
      #pragma unroll
      for (int ni = 0; ni < 4; ++ni)
        b[ni] = *(const bf16x8*)(sB + (wn * 64 + ni * 16 + l15) * 64 + (ko ^ ksw));
      #pragma unroll
      for (int mi = 0; mi < 4; ++mi)
        #pragma unroll
        for (int ni = 0; ni < 4; ++ni)
          acc[mi][ni] = __builtin_amdgcn_mfma_f32_16x16x32_bf16(a[mi], b[ni], acc[mi][ni], 0, 0, 0);
    }
    __builtin_amdgcn_s_setprio(0);
    __syncthreads();
  }

  #pragma unroll
  for (int mi = 0; mi < 4; ++mi) {
    #pragma unroll
    for (int r = 0; r < 4; ++r) {
      const int slot = m0 + wm * 64 + mi * 16 + (lane >> 4) * 4 + r;
      if (slot < cnte) {
        unsigned short* pr = po + (long)(be + slot) * H_DIM + n0 + wn * 64;
        #pragma unroll
        for (int ni = 0; ni < 4; ++ni)
          pr[ni * 16 + l15] = f2bf(acc[mi][ni][r]);
      }
    }
  }
}

// ---------------------------------------------------------------------------
// Combine: out[t][h] = sum of token's 8 routed partial rows + shared row.
// ---------------------------------------------------------------------------
__global__ __launch_bounds__(256) void combine_kernel(
    const unsigned short* __restrict__ po,
    const int* __restrict__ base,
    const unsigned int* __restrict__ tslot,
    float* __restrict__ out)
{
  const int t = blockIdx.x;
  __shared__ int rows[9];
  if (threadIdx.x < 8) {
    const unsigned int pr = tslot[t * 8 + threadIdx.x];
    rows[threadIdx.x] = base[pr >> 16] + (int)(pr & 0xFFFFu);
  }
  if (threadIdx.x == 8) rows[8] = base[32] + t;
  __syncthreads();
  const int col = threadIdx.x * 8;
  float s[8];
  #pragma unroll
  for (int j = 0; j < 8; ++j) s[j] = 0.f;
  #pragma unroll
  for (int k = 0; k < 9; ++k) {
    const ushort4* p = (const ushort4*)(po + (long)rows[k] * H_DIM + col);
    const ushort4 v0 = p[0], v1 = p[1];
    s[0] += __uint_as_float((unsigned int)v0.x << 16);
    s[1] += __uint_as_float((unsigned int)v0.y << 16);
    s[2] += __uint_as_float((unsigned int)v0.z << 16);
    s[3] += __uint_as_float((unsigned int)v0.w << 16);
    s[4] += __uint_as_float((unsigned int)v1.x << 16);
    s[5] += __uint_as_float((unsigned int)v1.y << 16);
    s[6] += __uint_as_float((unsigned int)v1.z << 16);
    s[7] += __uint_as_float((unsigned int)v1.w << 16);
  }
  float4 o0 = {s[0], s[1], s[2], s[3]};
  float4 o1 = {s[4], s[5], s[6], s[7]};
  *(float4*)(out + (long)t * H_DIM + col) = o0;
  *(float4*)(out + (long)t * H_DIM + col + 4) = o1;
}

// ---------------------------------------------------------------------------
extern "C" void kernel_launch(void* const* d_in, const int* in_sizes, int n_in,
                              void* d_out, int out_size, void* d_ws, size_t ws_size,
                              hipStream_t stream) {
  (void)in_sizes; (void)n_in; (void)out_size; (void)ws_size;
  const float* x   = (const float*)d_in[0];
  const float* gw  = (const float*)d_in[1];
  const float* wg  = (const float*)d_in[2];
  const float* wu  = (const float*)d_in[3];
  const float* wd  = (const float*)d_in[4];
  const float* wsg = (const float*)d_in[5];
  const float* wsu = (const float*)d_in[6];
  const float* wsd = (const float*)d_in[7];
  float* out = (float*)d_out;
  char* ws = (char*)d_ws;

  int*            cnt   = (int*)(ws + OFF_CNT);
  int*            ntgu  = (int*)(ws + OFF_NTGU);
  int*            ntdn  = (int*)(ws + OFF_NTDN);
  int*            basep = (int*)(ws + OFF_BASE);
  unsigned int*   tgu   = (unsigned int*)(ws + OFF_TGU);
  unsigned int*   tdn   = (unsigned int*)(ws + OFF_TDN);
  unsigned int*   pairs = (unsigned int*)(ws + OFF_PAIRS);
  unsigned int*   tslot = (unsigned int*)(ws + OFF_TSLOT);
  unsigned short* xb    = (unsigned short*)(ws + OFF_XB);
  unsigned short* wgT   = (unsigned short*)(ws + OFF_WGT);
  unsigned short* wuT   = (unsigned short*)(ws + OFF_WUT);
  unsigned short* wsgT  = (unsigned short*)(ws + OFF_WSGT);
  unsigned short* wsuT  = (unsigned short*)(ws + OFF_WSUT);
  unsigned short* wdT   = (unsigned short*)(ws + OFF_WDT);
  unsigned short* actb  = (unsigned short*)(ws + OFF_ACT);
  unsigned short* pob   = (unsigned short*)(ws + OFF_PO);   // aliases wgT

  hipMemsetAsync(ws + OFF_CNT, 0, 256, stream);

  router_kernel<<<T_TOK, 256, 0, stream>>>(x, gw, cnt, pairs, tslot, xb);
  build_tiles_kernel<<<1, 256, 0, stream>>>(cnt, basep, tgu, ntgu, tdn, ntdn,
                                            pairs);

  // fused transpose+cvt of all 6 weight tensors (64c x 256r tiles)
  TDescTable td;
  td.in[0] = wg;  td.out[0] = wgT;  td.C[0] = I_DIM;  td.ldout[0] = H_DIM;
  td.in_bs[0] = (long)H_DIM * I_DIM; td.out_bs[0] = (long)I_DIM * H_DIM;
  td.nbx[0] = I_DIM / 64; td.nbxy[0] = (I_DIM / 64) * (H_DIM / 256);
  td.in[1] = wu;  td.out[1] = wuT;  td.C[1] = I_DIM;  td.ldout[1] = H_DIM;
  td.in_bs[1] = (long)H_DIM * I_DIM; td.out_bs[1] = (long)I_DIM * H_DIM;
  td.nbx[1] = I_DIM / 64; td.nbxy[1] = (I_DIM / 64) * (H_DIM / 256);
  td.in[2] = wd;  td.out[2] = wdT;  td.C[2] = H_DIM;  td.ldout[2] = K_TOT;
  td.in_bs[2] = (long)I_DIM * H_DIM; td.out_bs[2] = (long)I_DIM;
  td.nbx[2] = H_DIM / 64; td.nbxy[2] = (H_DIM / 64) * (I_DIM / 256);
  td.in[3] = wsg; td.out[3] = wsgT; td.C[3] = IS_DIM; td.ldout[3] = H_DIM;
  td.in_bs[3] = 0; td.out_bs[3] = 0;
  td.nbx[3] = IS_DIM / 64; td.nbxy[3] = (IS_DIM / 64) * (H_DIM / 256);
  td.in[4] = wsu; td.out[4] = wsuT; td.C[4] = IS_DIM; td.ldout[4] = H_DIM;
  td.in_bs[4] = 0; td.out_bs[4] = 0;
  td.nbx[4] = IS_DIM / 64; td.nbxy[4] = (IS_DIM / 64) * (H_DIM / 256);
  td.in[5] = wsd; td.out[5] = wdT + E_NUM * I_DIM; td.C[5] = H_DIM;
  td.ldout[5] = K_TOT; td.in_bs[5] = 0; td.out_bs[5] = 0;
  td.nbx[5] = H_DIM / 64; td.nbxy[5] = (H_DIM / 64) * (IS_DIM / 256);
  td.start[0] = 0;
  for (int i = 0; i < 5; ++i) {
    int nz = (i <= 2) ? E_NUM : 1;
    td.start[i + 1] = td.start[i] + td.nbxy[i] * nz;
  }
  td.start[6] = td.start[5] + td.nbxy[5];
  transpose_fused<<<td.start[6], 256, 0, stream>>>(td);

  // gate+up (routed + shared pseudo-experts) -> compact act  [BN=128]
  gate_up_moe_kernel<<<dim3(8, GU_TILES), 512, 0, stream>>>(
      xb, wgT, wuT, wsgT, wsuT, cnt, basep, pairs, tgu, ntgu, actb);

  // down (routed K=1024, shared K=2048) -> plain-store partials (po aliases
  // wgT, dead after gate_up)
  down_moe_kernel<<<dim3(16, DN_TILES), 256, 0, stream>>>(
      actb, wdT, cnt, basep, tdn, ntdn, pob);

  // gather-combine: 9 partial rows per token -> out
  combine_kernel<<<T_TOK, 256, 0, stream>>>(pob, basep, tslot, out);
}

// Round 17
// 746.186 us; speedup vs baseline: 1.4229x; 1.0023x over previous
//
#include <hip/hip_runtime.h>

// Problem dims (fixed by the reference)
#define T_TOK 2048      // B*S tokens
#define H_DIM 2048
#define E_NUM 32
#define I_DIM 1024
#define IS_DIM 2048
#define K_TOT (E_NUM * I_DIM + IS_DIM)   // 34816
#define SLOT_CAP 2048
#define NE_ALL 34        // 32 routed + 2 shared pseudo-experts
#define GU_TILES 192     // <=160 routed + 32 shared (step 128)
#define DN_TILES 176     // <=160 routed + 16 shared (K=2048)
#define ACT_SLOTS 24576  // sum pad128(cnt_e) (<=20448) + 4096 shared

typedef __bf16 bf16x8 __attribute__((ext_vector_type(8)));
typedef float  f32x4  __attribute__((ext_vector_type(4)));
static_assert(sizeof(bf16x8) == 16, "bf16x8 must be 16B");

// Workspace layout (bytes). Total = 486,885,376.
// po [ACT_SLOTS][H] bf16 (100.7 MB) ALIASES wgT (dead after gate_up).
#define OFF_CNT   ((size_t)0)            // cnt[34] int
#define OFF_NTGU  ((size_t)192)
#define OFF_NTDN  ((size_t)196)
#define OFF_BASE  ((size_t)256)          // base[34] int
#define OFF_TGU   ((size_t)512)          // tilesGU[192] uint
#define OFF_TDN   ((size_t)1280)         // tilesDN[176] uint
#define OFF_PAIRS ((size_t)2048)         // pairs[34][2048] uint = 278,528
#define OFF_XB    ((size_t)280576)       // xb [T,H] bf16 = 8,388,608
#define OFF_WGT   ((size_t)8669184)      // wgT [E][I][H] bf16 (po aliases)
#define OFF_PO    OFF_WGT
#define OFF_WUT   ((size_t)142886912)    // wuT [E][I][H] bf16
#define OFF_WSGT  ((size_t)277104640)    // wsgT [IS][H] bf16
#define OFF_WSUT  ((size_t)285493248)    // wsuT [IS][H] bf16
#define OFF_WDT   ((size_t)293881856)    // wdT [H][K_TOT] bf16
#define OFF_ACT   ((size_t)436488192)    // act [24576][1024] bf16 = 50,331,648
#define OFF_TSLOT ((size_t)486819840)    // tslot[T][8] uint = 65,536

__device__ __forceinline__ unsigned short f2bf(float f) {
  unsigned int u = __float_as_uint(f);
  u += 0x7fffu + ((u >> 16) & 1u);   // round-to-nearest-even
  return (unsigned short)(u >> 16);
}

__device__ __forceinline__ void gld16(const void* g, void* l) {
  __builtin_amdgcn_global_load_lds(
      (const __attribute__((address_space(1))) unsigned int*)g,
      (__attribute__((address_space(3))) unsigned int*)l, 16, 0, 0);
}

// ---------------------------------------------------------------------------
// Router: sigmoid(x @ gw^T); top-8; renorm; *2.5 -> pair lists + tslot + xb.
// ---------------------------------------------------------------------------
__global__ __launch_bounds__(256) void router_kernel(
    const float* __restrict__ x, const float* __restrict__ gw,
    int* __restrict__ cnt, unsigned int* __restrict__ pairs,
    unsigned int* __restrict__ tslot, unsigned short* __restrict__ xb)
{
  const int t = blockIdx.x;
  __shared__ float xs[H_DIM];
  __shared__ float sc[E_NUM];
  const float4* xr = (const float4*)(x + (long)t * H_DIM);
  for (int i = threadIdx.x; i < H_DIM / 4; i += 256) ((float4*)xs)[i] = xr[i];
  __syncthreads();
  {
    const int i0 = threadIdx.x * 8;
    ushort4 o1, o2;
    o1.x = f2bf(xs[i0 + 0]); o1.y = f2bf(xs[i0 + 1]);
    o1.z = f2bf(xs[i0 + 2]); o1.w = f2bf(xs[i0 + 3]);
    o2.x = f2bf(xs[i0 + 4]); o2.y = f2bf(xs[i0 + 5]);
    o2.z = f2bf(xs[i0 + 6]); o2.w = f2bf(xs[i0 + 7]);
    *(ushort4*)(xb + (long)t * H_DIM + i0) = o1;
    *(ushort4*)(xb + (long)t * H_DIM + i0 + 4) = o2;
  }
  const int e = threadIdx.x >> 3, p = threadIdx.x & 7;
  const float4* ga = (const float4*)(gw + (long)e * H_DIM);
  const float4* xa = (const float4*)xs;
  float s = 0.f;
  #pragma unroll 4
  for (int i = p * 64; i < p * 64 + 64; ++i) {
    float4 a = ga[i], b = xa[i];
    s += a.x * b.x + a.y * b.y + a.z * b.z + a.w * b.w;
  }
  s += __shfl_down(s, 4, 8);
  s += __shfl_down(s, 2, 8);
  s += __shfl_down(s, 1, 8);
  if (p == 0) sc[e] = 1.f / (1.f + expf(-s));
  __syncthreads();
  if (threadIdx.x == 0) {
    float v[E_NUM];
    #pragma unroll
    for (int i = 0; i < E_NUM; ++i) v[i] = sc[i];
    unsigned mask = 0; float sum = 0.f;
    int sel[8]; float wv[8];
    for (int k = 0; k < 8; ++k) {
      float best = -1.f; int bi = 0;
      for (int i = 0; i < E_NUM; ++i)
        if (!((mask >> i) & 1u) && v[i] > best) { best = v[i]; bi = i; }
      mask |= 1u << bi; sel[k] = bi; wv[k] = best; sum += best;
    }
    const float scale = 2.5f / (sum + 1e-20f);
    for (int k = 0; k < 8; ++k) {
      const int slot = atomicAdd(&cnt[sel[k]], 1);
      if (slot < SLOT_CAP) {
        const unsigned int w16 = (unsigned int)f2bf(wv[k] * scale);
        pairs[sel[k] * SLOT_CAP + slot] = (w16 << 16) | (unsigned int)t;
        tslot[t * 8 + k] = ((unsigned int)sel[k] << 16) | (unsigned int)slot;
      }
    }
  }
}

// ---------------------------------------------------------------------------
// Build tile lists (step 128) + pad128 act bases; fill shared pseudo pairs.
// ---------------------------------------------------------------------------
__global__ __launch_bounds__(256) void build_tiles_kernel(
    int* __restrict__ cnt, int* __restrict__ base,
    unsigned int* __restrict__ tgu, int* __restrict__ ntgu,
    unsigned int* __restrict__ tdn, int* __restrict__ ntdn,
    unsigned int* __restrict__ pairs)
{
  const int t = threadIdx.x;
  for (int s = t; s < T_TOK; s += 256) {
    const unsigned int pv = (0x3F80u << 16) | (unsigned int)s;  // w=1.0 bf16
    pairs[32 * SLOT_CAP + s] = pv;
    pairs[33 * SLOT_CAP + s] = pv;
  }
  if (t == 0) {
    cnt[32] = T_TOK; cnt[33] = T_TOK;
    int b = 0, ngu = 0, ndn = 0;
    for (int e = 0; e < NE_ALL; ++e) {
      const int c = (e < 32) ? cnt[e] : T_TOK;
      base[e] = b;
      for (int m0 = 0; m0 < c; m0 += 128) {
        tgu[ngu++] = ((unsigned int)e << 16) | (unsigned int)m0;
        if (e < 33) tdn[ndn++] = ((unsigned int)e << 16) | (unsigned int)m0;
      }
      b += (c + 127) & ~127;
    }
    *ntgu = ngu; *ntdn = ndn;
  }
}

// ---------------------------------------------------------------------------
// Transpose+cvt, 64(c) x 128(r) tiles (16.6KB LDS -> 8 blocks/CU, 2x the
// prior occupancy; 8 float4/thread = 32 VGPR so the load batch actually
// stays in flight — the 256r version's VGPR=52 proved the compiler
// re-serialized 16 loads). ld=130 shorts (65 dwords, odd) keeps LDS writes
// 2-way-free and reads at the b128 minimum.
// ---------------------------------------------------------------------------
struct TDescTable {
  const float* in[6];
  unsigned short* out[6];
  int C[6];
  int ldout[6];
  long in_bs[6];
  long out_bs[6];
  int nbx[6];
  int nbxy[6];
  int start[7];
};

__global__ __launch_bounds__(256) void transpose_fused(TDescTable td)
{
  const int bid = blockIdx.x;
  int i = 0;
  while (i < 5 && bid >= td.start[i + 1]) ++i;
  const int local = bid - td.start[i];
  const int bz = local / td.nbxy[i];
  const int rem = local % td.nbxy[i];
  const int by = rem / td.nbx[i];
  const int bx = rem % td.nbx[i];
  const float* in = td.in[i] + (long)bz * td.in_bs[i];
  unsigned short* out = td.out[i] + (long)bz * td.out_bs[i];
  const int C = td.C[i], ldout = td.ldout[i];

  __shared__ unsigned short tile[64][130];
  const int c0 = bx * 64;
  const int r0 = by * 128;
  const int t = threadIdx.x;
  const int rl0 = t >> 4;          // 0..15
  const int cl0 = (t & 15) * 4;    // 0..60

  float4 v[8];
  #pragma unroll
  for (int p = 0; p < 8; ++p) {
    const int rl = p * 16 + rl0;
    v[p] = *(const float4*)(in + (long)(r0 + rl) * C + c0 + cl0);
  }
  __builtin_amdgcn_sched_barrier(0);
  #pragma unroll
  for (int p = 0; p < 8; ++p) {
    const int rl = p * 16 + rl0;
    tile[cl0 + 0][rl] = f2bf(v[p].x);
    tile[cl0 + 1][rl] = f2bf(v[p].y);
    tile[cl0 + 2][rl] = f2bf(v[p].z);
    tile[cl0 + 3][rl] = f2bf(v[p].w);
  }
  __syncthreads();
  const int cw = t >> 4;           // 0..15
  const int rw = (t & 15) * 8;     // 0..120
  #pragma unroll
  for (int q = 0; q < 4; ++q) {
    const int cl = q * 16 + cw;
    const char* src = (const char*)&tile[cl][rw];  // 4B-aligned
    uint4 o;
    o.x = *(const unsigned int*)(src + 0);
    o.y = *(const unsigned int*)(src + 4);
    o.z = *(const unsigned int*)(src + 8);
    o.w = *(const unsigned int*)(src + 12);
    *(uint4*)(out + (long)(c0 + cl) * ldout + r0 + rw) = o;
  }
}

// ---------------------------------------------------------------------------
// Gate+up GEMM: 512 thr (8 waves, 2Mx4N), block 128(slots) x 128(n), BK=64,
// per-wave tile 64x32, single-buf 48KB LDS, 2-barrier K-loop, XOR-swizzled
// LDS, gathered A rows, setprio around MFMA.
// ---------------------------------------------------------------------------
__global__ __launch_bounds__(512) void gate_up_moe_kernel(
    const unsigned short* __restrict__ xb,
    const unsigned short* __restrict__ bgT,
    const unsigned short* __restrict__ buT,
    const unsigned short* __restrict__ sgT,
    const unsigned short* __restrict__ suT,
    const int* __restrict__ cnt,
    const int* __restrict__ base,
    const unsigned int* __restrict__ pairs,
    const unsigned int* __restrict__ tiles,
    const int* __restrict__ ntp,
    unsigned short* __restrict__ act)
{
  const int ti = blockIdx.y;
  if (ti >= *ntp) return;
  const unsigned int tile = tiles[ti];
  const int e  = (int)(tile >> 16);
  const int m0 = (int)(tile & 0xFFFFu);
  const int cnte = cnt[e];
  const int be = base[e];
  const int n0 = blockIdx.x * 128;
  const long panel = (long)I_DIM * H_DIM;
  const unsigned short* Bg =
      ((e < 32) ? bgT + e * panel : sgT + (e - 32) * panel) + (long)n0 * H_DIM;
  const unsigned short* Bu =
      ((e < 32) ? buT + e * panel : suT + (e - 32) * panel) + (long)n0 * H_DIM;

  __shared__ unsigned short sA[128 * 64];    // 16KB
  __shared__ unsigned short sBg[128 * 64];   // 16KB
  __shared__ unsigned short sBu[128 * 64];   // 16KB

  const int tid = threadIdx.x;
  const int lane = tid & 63;
  const int wid = tid >> 6;            // 0..7
  const int wm = wid >> 2, wn = wid & 3;
  const int l15 = lane & 15;
  const int lk  = (lane >> 4) * 8;
  const int srow = tid >> 3;           // 0..63
  const int scol = (tid & 7) * 8;
  const int scolsw = (((tid & 7) ^ (srow & 7))) * 8;
  const int ksw = (l15 & 7) << 3;

  const unsigned short* asrc[2];
  #pragma unroll
  for (int r = 0; r < 2; ++r) {
    const int slot = m0 + r * 64 + srow;
    const unsigned int pr = (slot < cnte) ? pairs[e * SLOT_CAP + slot] : 0u;
    asrc[r] = xb + (long)(pr & 0xFFFFu) * H_DIM + scolsw;
  }

  const f32x4 fz = {0.f, 0.f, 0.f, 0.f};
  f32x4 accg[4][2], accu[4][2];
  #pragma unroll
  for (int i = 0; i < 4; ++i)
    #pragma unroll
    for (int j = 0; j < 2; ++j) { accg[i][j] = fz; accu[i][j] = fz; }

  for (int k0 = 0; k0 < H_DIM; k0 += 64) {
    #pragma unroll
    for (int r = 0; r < 2; ++r) {
      gld16(asrc[r] + k0, sA + (r * 64 + srow) * 64 + scol);
      gld16(Bg + (long)(r * 64 + srow) * H_DIM + k0 + scolsw,
            sBg + (r * 64 + srow) * 64 + scol);
      gld16(Bu + (long)(r * 64 + srow) * H_DIM + k0 + scolsw,
            sBu + (r * 64 + srow) * 64 + scol);
    }
    __syncthreads();
    __builtin_amdgcn_s_setprio(1);
    #pragma unroll
    for (int kk = 0; kk < 2; ++kk) {
      const int ko = kk * 32 + lk;
      bf16x8 a[4], g[2], u[2];
      #pragma unroll
      for (int mi = 0; mi < 4; ++mi)
        a[mi] = *(const bf16x8*)(sA + (wm * 64 + mi * 16 + l15) * 64 + (ko ^ ksw));
      #pragma unroll
      for (int ni = 0; ni < 2; ++ni) {
        g[ni] = *(const bf16x8*)(sBg + (wn * 32 + ni * 16 + l15) * 64 + (ko ^ ksw));
        u[ni] = *(const bf16x8*)(sBu + (wn * 32 + ni * 16 + l15) * 64 + (ko ^ ksw));
      }
      #pragma unroll
      for (int mi = 0; mi < 4; ++mi)
        #pragma unroll
        for (int ni = 0; ni < 2; ++ni) {
          accg[mi][ni] = __builtin_amdgcn_mfma_f32_16x16x32_bf16(a[mi], g[ni], accg[mi][ni], 0, 0, 0);
          accu[mi][ni] = __builtin_amdgcn_mfma_f32_16x16x32_bf16(a[mi], u[ni], accu[mi][ni], 0, 0, 0);
        }
    }
    __builtin_amdgcn_s_setprio(0);
    __syncthreads();
  }

  const int colb = n0 + wn * 32;
  #pragma unroll
  for (int mi = 0; mi < 4; ++mi) {
    #pragma unroll
    for (int r = 0; r < 4; ++r) {
      const int slot = m0 + wm * 64 + mi * 16 + (lane >> 4) * 4 + r;
      if (slot < cnte) {
        const unsigned int pr = pairs[e * SLOT_CAP + slot];
        const float w = __uint_as_float(pr & 0xFFFF0000u);
        #pragma unroll
        for (int ni = 0; ni < 2; ++ni) {
          const float gv = accg[mi][ni][r];
          const float uv = accu[mi][ni][r];
          const float sv = (gv / (1.f + expf(-gv))) * uv * w;
          act[((long)(be + slot)) * I_DIM + colb + ni * 16 + l15] = f2bf(sv);
        }
      }
    }
  }
}

// ---------------------------------------------------------------------------
// Down GEMM (round-12 geometry): 256 thr, 4 waves (2Mx2N), wave tile 64x64,
// block 128x128, single-buf 32KB LDS, 2-barrier loop. e=32 runs K=2048.
// Plain bf16 stores to po (combine kernel sums).
// ---------------------------------------------------------------------------
__global__ __launch_bounds__(256) void down_moe_kernel(
    const unsigned short* __restrict__ act,
    const unsigned short* __restrict__ wdT,
    const int* __restrict__ cnt,
    const int* __restrict__ base,
    const unsigned int* __restrict__ tiles,
    const int* __restrict__ ntp,
    unsigned short* __restrict__ po)
{
  const int ti = blockIdx.y;
  if (ti >= *ntp) return;
  const unsigned int tile = tiles[ti];
  const int e  = (int)(tile >> 16);
  const int m0 = (int)(tile & 0xFFFFu);
  const int cnte = cnt[e];
  const int be = base[e];
  const int n0 = blockIdx.x * 128;
  const unsigned short* A = act + ((long)be + m0) * I_DIM;
  const unsigned short* B = wdT + (long)n0 * K_TOT + (long)e * I_DIM;
  const int nk = (e == 32) ? 32 : 16;

  __shared__ unsigned short sA[128 * 64];
  __shared__ unsigned short sB[128 * 64];

  const int tid = threadIdx.x;
  const int lane = tid & 63;
  const int wid = tid >> 6;
  const int wm = wid >> 1, wn = wid & 1;
  const int l15 = lane & 15;
  const int lk  = (lane >> 4) * 8;
  const int srow = tid >> 3;
  const int scol = (tid & 7) * 8;
  const int scolsw = (((tid & 7) ^ (srow & 7))) * 8;
  const int ksw = (l15 & 7) << 3;

  const f32x4 fz = {0.f, 0.f, 0.f, 0.f};
  f32x4 acc[4][4];
  #pragma unroll
  for (int i = 0; i < 4; ++i)
    #pragma unroll
    for (int j = 0; j < 4; ++j) acc[i][j] = fz;

  for (int t = 0; t < nk; ++t) {
    const int k0 = t * 64;
    const long koff = (long)(k0 & 1023) + (long)(k0 >> 10) * (2048L * 1024L);
    #pragma unroll
    for (int r = 0; r < 4; ++r)
      gld16(A + (long)(r * 32 + srow) * I_DIM + koff + scolsw,
            sA + (r * 32 + srow) * 64 + scol);
    #pragma unroll
    for (int r = 0; r < 4; ++r)
      gld16(B + (long)(r * 32 + srow) * K_TOT + k0 + scolsw,
            sB + (r * 32 + srow) * 64 + scol);
    __syncthreads();
    __builtin_amdgcn_s_setprio(1);
    #pragma unroll
    for (int kk = 0; kk < 2; ++kk) {
      const int ko = kk * 32 + lk;
      bf16x8 a[4], b[4];
      #pragma unroll
      for (int mi = 0; mi < 4; ++mi)
        a[mi] = *(const bf16x8*)(sA + (wm * 64 + mi * 16 + l15) * 64 + (ko ^ ksw));
      #pragma unroll
      for (int ni = 0; ni < 4; ++ni)
        b[ni] = *(const bf16x8*)(sB + (wn * 64 + ni * 16 + l15) * 64 + (ko ^ ksw));
      #pragma unroll
      for (int mi = 0; mi < 4; ++mi)
        #pragma unroll
        for (int ni = 0; ni < 4; ++ni)
          acc[mi][ni] = __builtin_amdgcn_mfma_f32_16x16x32_bf16(a[mi], b[ni], acc[mi][ni], 0, 0, 0);
    }
    __builtin_amdgcn_s_setprio(0);
    __syncthreads();
  }

  #pragma unroll
  for (int mi = 0; mi < 4; ++mi) {
    #pragma unroll
    for (int r = 0; r < 4; ++r) {
      const int slot = m0 + wm * 64 + mi * 16 + (lane >> 4) * 4 + r;
      if (slot < cnte) {
        unsigned short* pr = po + (long)(be + slot) * H_DIM + n0 + wn * 64;
        #pragma unroll
        for (int ni = 0; ni < 4; ++ni)
          pr[ni * 16 + l15] = f2bf(acc[mi][ni][r]);
      }
    }
  }
}

// ---------------------------------------------------------------------------
// Combine: out[t][h] = sum of token's 8 routed partial rows + shared row.
// ---------------------------------------------------------------------------
__global__ __launch_bounds__(256) void combine_kernel(
    const unsigned short* __restrict__ po,
    const int* __restrict__ base,
    const unsigned int* __restrict__ tslot,
    float* __restrict__ out)
{
  const int t = blockIdx.x;
  __shared__ int rows[9];
  if (threadIdx.x < 8) {
    const unsigned int pr = tslot[t * 8 + threadIdx.x];
    rows[threadIdx.x] = base[pr >> 16] + (int)(pr & 0xFFFFu);
  }
  if (threadIdx.x == 8) rows[8] = base[32] + t;
  __syncthreads();
  const int col = threadIdx.x * 8;
  float s[8];
  #pragma unroll
  for (int j = 0; j < 8; ++j) s[j] = 0.f;
  #pragma unroll
  for (int k = 0; k < 9; ++k) {
    const ushort4* p = (const ushort4*)(po + (long)rows[k] * H_DIM + col);
    const ushort4 v0 = p[0], v1 = p[1];
    s[0] += __uint_as_float((unsigned int)v0.x << 16);
    s[1] += __uint_as_float((unsigned int)v0.y << 16);
    s[2] += __uint_as_float((unsigned int)v0.z << 16);
    s[3] += __uint_as_float((unsigned int)v0.w << 16);
    s[4] += __uint_as_float((unsigned int)v1.x << 16);
    s[5] += __uint_as_float((unsigned int)v1.y << 16);
    s[6] += __uint_as_float((unsigned int)v1.z << 16);
    s[7] += __uint_as_float((unsigned int)v1.w << 16);
  }
  float4 o0 = {s[0], s[1], s[2], s[3]};
  float4 o1 = {s[4], s[5], s[6], s[7]};
  *(float4*)(out + (long)t * H_DIM + col) = o0;
  *(float4*)(out + (long)t * H_DIM + col + 4) = o1;
}

// ---------------------------------------------------------------------------
extern "C" void kernel_launch(void* const* d_in, const int* in_sizes, int n_in,
                              void* d_out, int out_size, void* d_ws, size_t ws_size,
                              hipStream_t stream) {
  (void)in_sizes; (void)n_in; (void)out_size; (void)ws_size;
  const float* x   = (const float*)d_in[0];
  const float* gw  = (const float*)d_in[1];
  const float* wg  = (const float*)d_in[2];
  const float* wu  = (const float*)d_in[3];
  const float* wd  = (const float*)d_in[4];
  const float* wsg = (const float*)d_in[5];
  const float* wsu = (const float*)d_in[6];
  const float* wsd = (const float*)d_in[7];
  float* out = (float*)d_out;
  char* ws = (char*)d_ws;

  int*            cnt   = (int*)(ws + OFF_CNT);
  int*            ntgu  = (int*)(ws + OFF_NTGU);
  int*            ntdn  = (int*)(ws + OFF_NTDN);
  int*            basep = (int*)(ws + OFF_BASE);
  unsigned int*   tgu   = (unsigned int*)(ws + OFF_TGU);
  unsigned int*   tdn   = (unsigned int*)(ws + OFF_TDN);
  unsigned int*   pairs = (unsigned int*)(ws + OFF_PAIRS);
  unsigned int*   tslot = (unsigned int*)(ws + OFF_TSLOT);
  unsigned short* xb    = (unsigned short*)(ws + OFF_XB);
  unsigned short* wgT   = (unsigned short*)(ws + OFF_WGT);
  unsigned short* wuT   = (unsigned short*)(ws + OFF_WUT);
  unsigned short* wsgT  = (unsigned short*)(ws + OFF_WSGT);
  unsigned short* wsuT  = (unsigned short*)(ws + OFF_WSUT);
  unsigned short* wdT   = (unsigned short*)(ws + OFF_WDT);
  unsigned short* actb  = (unsigned short*)(ws + OFF_ACT);
  unsigned short* pob   = (unsigned short*)(ws + OFF_PO);   // aliases wgT

  hipMemsetAsync(ws + OFF_CNT, 0, 256, stream);

  router_kernel<<<T_TOK, 256, 0, stream>>>(x, gw, cnt, pairs, tslot, xb);
  build_tiles_kernel<<<1, 256, 0, stream>>>(cnt, basep, tgu, ntgu, tdn, ntdn,
                                            pairs);

  // fused transpose+cvt of all 6 weight tensors (64c x 128r tiles)
  TDescTable td;
  td.in[0] = wg;  td.out[0] = wgT;  td.C[0] = I_DIM;  td.ldout[0] = H_DIM;
  td.in_bs[0] = (long)H_DIM * I_DIM; td.out_bs[0] = (long)I_DIM * H_DIM;
  td.nbx[0] = I_DIM / 64; td.nbxy[0] = (I_DIM / 64) * (H_DIM / 128);
  td.in[1] = wu;  td.out[1] = wuT;  td.C[1] = I_DIM;  td.ldout[1] = H_DIM;
  td.in_bs[1] = (long)H_DIM * I_DIM; td.out_bs[1] = (long)I_DIM * H_DIM;
  td.nbx[1] = I_DIM / 64; td.nbxy[1] = (I_DIM / 64) * (H_DIM / 128);
  td.in[2] = wd;  td.out[2] = wdT;  td.C[2] = H_DIM;  td.ldout[2] = K_TOT;
  td.in_bs[2] = (long)I_DIM * H_DIM; td.out_bs[2] = (long)I_DIM;
  td.nbx[2] = H_DIM / 64; td.nbxy[2] = (H_DIM / 64) * (I_DIM / 128);
  td.in[3] = wsg; td.out[3] = wsgT; td.C[3] = IS_DIM; td.ldout[3] = H_DIM;
  td.in_bs[3] = 0; td.out_bs[3] = 0;
  td.nbx[3] = IS_DIM / 64; td.nbxy[3] = (IS_DIM / 64) * (H_DIM / 128);
  td.in[4] = wsu; td.out[4] = wsuT; td.C[4] = IS_DIM; td.ldout[4] = H_DIM;
  td.in_bs[4] = 0; td.out_bs[4] = 0;
  td.nbx[4] = IS_DIM / 64; td.nbxy[4] = (IS_DIM / 64) * (H_DIM / 128);
  td.in[5] = wsd; td.out[5] = wdT + E_NUM * I_DIM; td.C[5] = H_DIM;
  td.ldout[5] = K_TOT; td.in_bs[5] = 0; td.out_bs[5] = 0;
  td.nbx[5] = H_DIM / 64; td.nbxy[5] = (H_DIM / 64) * (IS_DIM / 128);
  td.start[0] = 0;
  for (int i = 0; i < 5; ++i) {
    int nz = (i <= 2) ? E_NUM : 1;
    td.start[i + 1] = td.start[i] + td.nbxy[i] * nz;
  }
  td.start[6] = td.start[5] + td.nbxy[5];
  transpose_fused<<<td.start[6], 256, 0, stream>>>(td);

  // gate+up (routed + shared pseudo-experts) -> compact act  [BN=128]
  gate_up_moe_kernel<<<dim3(8, GU_TILES), 512, 0, stream>>>(
      xb, wgT, wuT, wsgT, wsuT, cnt, basep, pairs, tgu, ntgu, actb);

  // down (routed K=1024, shared K=2048) -> plain-store partials (po aliases
  // wgT, dead after gate_up)
  down_moe_kernel<<<dim3(16, DN_TILES), 256, 0, stream>>>(
      actb, wdT, cnt, basep, tdn, ntdn, pob);

  // gather-combine: 9 partial rows per token -> out
  combine_kernel<<<T_TOK, 256, 0, stream>>>(pob, basep, tslot, out);
}